// Round 2
// baseline (689.325 us; speedup 1.0000x reference)
//
#include <hip/hip_runtime.h>
#include <hip/hip_bf16.h>

// SAKE GNN: B=512 graphs, M=32 atoms, H=128, L=2 layers, F_IN=16.
// Block = one graph, 512 threads (8 waves). All GEMMs via mfma_f32_16x16x32_bf16.
//
// R1 fix: __launch_bounds__(512, 2) — min 2 waves/EU = 1 block/CU = 256-VGPR
// budget. R0's implicit 128-VGPR target spilled the 128-VGPR hoisted We2^T
// fragment array to scratch (527 MB WRITE_SIZE / 992 MB FETCH_SIZE of HBM
// spill traffic = the whole 677 us). Occupancy was already ~1 block/CU, so
// the bigger register budget is free.

#define NB 512
#define NM 32
#define NH 128

typedef __bf16 bf16x8 __attribute__((ext_vector_type(8)));
typedef unsigned short u16x8 __attribute__((ext_vector_type(8)));
typedef float f32x4 __attribute__((ext_vector_type(4)));

__device__ __forceinline__ unsigned short f2bf(float f) {
    unsigned int u = __float_as_uint(f);
    u = u + 0x7FFFu + ((u >> 16) & 1u);   // RNE
    return (unsigned short)(u >> 16);
}
__device__ __forceinline__ float bf2f(unsigned short s) {
    return __uint_as_float(((unsigned int)s) << 16);
}
__device__ __forceinline__ float silu_f(float v) {
    return v / (1.0f + __expf(-v));
}

// ---------------- weight transpose+bf16 prep into workspace ----------------
// ws layout (each matrix 128x128 = 16384 bf16, stored as WT[n][k] = W[k][n]):
//   l*6 + {0:WaT, 1:WbT, 2:We2T, 3:Wh1aT, 4:Wh1bT, 5:Wh2T}, 12:W_outT, 13:Wn1T
__global__ void prep_weights(const float* __restrict__ We1, const float* __restrict__ We2,
                             const float* __restrict__ Wh1, const float* __restrict__ Wh2,
                             const float* __restrict__ W_out, const float* __restrict__ Wn1,
                             unsigned short* __restrict__ ws) {
    int gid = blockIdx.x * blockDim.x + threadIdx.x;
    if (gid >= 14 * 16384) return;
    int mtx = gid >> 14;
    int el  = gid & 16383;
    int n = el >> 7, k = el & 127;
    int l    = (mtx < 12) ? (mtx / 6) : 0;
    int kind = (mtx < 12) ? (mtx % 6) : (6 + (mtx - 12));
    float v = 0.f;
    switch (kind) {
        case 0: v = We1[(l*257 +       k)*128 + n]; break;   // Wa = We1[l, :128]
        case 1: v = We1[(l*257 + 128 + k)*128 + n]; break;   // Wb = We1[l, 128:256]
        case 2: v = We2[(l*128 +       k)*128 + n]; break;
        case 3: v = Wh1[(l*256 +       k)*128 + n]; break;   // Wh1a
        case 4: v = Wh1[(l*256 + 128 + k)*128 + n]; break;   // Wh1b
        case 5: v = Wh2[(l*128 +       k)*128 + n]; break;
        case 6: v = W_out[k*128 + n]; break;
        case 7: v = Wn1[k*128 + n]; break;
    }
    ws[gid] = f2bf(v);
}

// ---------------- main fused kernel ----------------
__global__ __launch_bounds__(512, 2) void sake_kernel(
    const float* __restrict__ h,   const float* __restrict__ x,
    const float* __restrict__ W_in,const float* __restrict__ b_in,
    const float* __restrict__ We1, const float* __restrict__ be1,
    const float* __restrict__ be2, const float* __restrict__ bh1,
    const float* __restrict__ bh2, const float* __restrict__ b_out,
    const float* __restrict__ bn1, const float* __restrict__ Wn2,
    const float* __restrict__ bn2, const unsigned short* __restrict__ wt,
    float* __restrict__ out)
{
    __shared__ __align__(16) float          s_d2[32*32];      // 4 KB
    __shared__ __align__(16) float          s_hg[32*129];     // 16.1 KB fp32 residual
    __shared__ __align__(16) unsigned short s_mimj[32*264];   // 16.5 KB bf16 (mi | mj+be1); reused as g fp32
    __shared__ __align__(16) unsigned short s_A1[32*136];     // 8.5 KB bf16 A-stage (hgb / ub)
    __shared__ __align__(16) unsigned short s_A2[32*136];     // 8.5 KB bf16 A-stage (agg / ho)
    __shared__ __align__(16) float          s_wd[128];
    __shared__ __align__(16) float          s_x[32*4];
    __shared__ __align__(16) float          s_ep[256];

    const int tid  = threadIdx.x;
    const int b    = blockIdx.x;
    const int w    = tid >> 6;        // wave 0..7
    const int lane = tid & 63;
    const int quad = lane >> 4;
    const int lm   = lane & 15;

    // ---- load x, d2, hg = h@W_in + b_in ----
    if (tid < 32) {
        s_x[tid*4+0] = x[(b*32+tid)*3+0];
        s_x[tid*4+1] = x[(b*32+tid)*3+1];
        s_x[tid*4+2] = x[(b*32+tid)*3+2];
    }
    __syncthreads();
    for (int p = tid; p < 1024; p += 512) {
        int i = p >> 5, j = p & 31;
        float dx = s_x[i*4+0]-s_x[j*4+0];
        float dy = s_x[i*4+1]-s_x[j*4+1];
        float dz = s_x[i*4+2]-s_x[j*4+2];
        s_d2[p] = dx*dx + dy*dy + dz*dz;
    }
    {
        int k = tid & 127, mg = tid >> 7;   // mg 0..3 -> 8 rows each
        float wcol[16];
        #pragma unroll
        for (int f = 0; f < 16; f++) wcol[f] = W_in[f*128 + k];
        float bi = b_in[k];
        for (int rr = 0; rr < 8; rr++) {
            int m = mg*8 + rr;
            const float4* h4 = (const float4*)(h + (size_t)(b*32 + m)*16);
            float acc = bi;
            #pragma unroll
            for (int q = 0; q < 4; q++) {
                float4 hv = h4[q];
                acc += hv.x*wcol[q*4+0] + hv.y*wcol[q*4+1]
                     + hv.z*wcol[q*4+2] + hv.w*wcol[q*4+3];
            }
            s_hg[m*129 + k] = acc;
        }
    }
    __syncthreads();

    for (int l = 0; l < 2; l++) {
        // ---- stage hg -> bf16 A1, load wd ----
        {
            int m = tid >> 4, c = (tid & 15) * 8;
            #pragma unroll
            for (int q = 0; q < 8; q++) s_A1[m*136 + c + q] = f2bf(s_hg[m*129 + c + q]);
        }
        if (tid < 128) s_wd[tid] = We1[(l*257 + 256)*128 + tid];
        __syncthreads();

        // ---- mi | mj GEMM: [32x128] @ [Wa | Wb] -> s_mimj (be1 folded into mj) ----
        {
            int mt = w & 1, ng = w >> 1;
            #pragma unroll
            for (int t4 = 0; t4 < 4; t4++) {
                int nt = ng + t4*4;                       // 0..15
                const unsigned short* bt = wt + (((size_t)l*6 + (nt < 8 ? 0 : 1)) << 14);
                int ncl = (nt & 7)*16 + lm;
                f32x4 acc = {0.f,0.f,0.f,0.f};
                #pragma unroll
                for (int kb = 0; kb < 4; kb++) {
                    bf16x8 a  = *(const bf16x8*)&s_A1[(mt*16+lm)*136 + kb*32 + quad*8];
                    bf16x8 bb = *(const bf16x8*)&bt[ncl*128 + kb*32 + quad*8];
                    acc = __builtin_amdgcn_mfma_f32_16x16x32_bf16(a, bb, acc, 0, 0, 0);
                }
                int c = nt*16 + lm;
                float bias = (nt >= 8) ? be1[l*128 + ncl] : 0.0f;
                #pragma unroll
                for (int r = 0; r < 4; r++)
                    s_mimj[(mt*16 + quad*4 + r)*264 + c] = f2bf(acc[r] + bias);
            }
        }
        __syncthreads();

        // ---- pair phase: silu1 -> (1024x128)@We2 -> silu2 -> mask -> agg ----
        {
            const unsigned short* we2t = wt + (((size_t)l*6 + 2) << 14);
            bf16x8 bfr[8][4];                              // hoisted We2^T B-frags (128 VGPR)
            #pragma unroll
            for (int nt = 0; nt < 8; nt++)
                #pragma unroll
                for (int kb = 0; kb < 4; kb++)
                    bfr[nt][kb] = *(const bf16x8*)&we2t[(nt*16+lm)*128 + kb*32 + quad*8];
            float be2v[8];
            #pragma unroll
            for (int nt = 0; nt < 8; nt++) be2v[nt] = be2[l*128 + nt*16 + lm];

            for (int ii = 0; ii < 4; ii++) {
                int i = ii*8 + w;                          // wave owns row i fully
                float vsum[8] = {0.f,0.f,0.f,0.f,0.f,0.f,0.f,0.f};
                #pragma unroll
                for (int g = 0; g < 2; g++) {
                    int j = g*16 + lm;
                    float d2v = s_d2[i*32 + j];
                    bf16x8 af[4];
                    #pragma unroll
                    for (int kb = 0; kb < 4; kb++) {
                        u16x8 miv = *(const u16x8*)&s_mimj[i*264 +       kb*32 + quad*8];
                        u16x8 mjv = *(const u16x8*)&s_mimj[j*264 + 128 + kb*32 + quad*8];
                        const float4* wd4 = (const float4*)&s_wd[kb*32 + quad*8];
                        float4 w0 = wd4[0], w1 = wd4[1];
                        float wdv[8] = {w0.x,w0.y,w0.z,w0.w,w1.x,w1.y,w1.z,w1.w};
                        u16x8 au;
                        #pragma unroll
                        for (int jj = 0; jj < 8; jj++) {
                            float a = bf2f(miv[jj]) + bf2f(mjv[jj]) + d2v*wdv[jj];
                            au[jj] = f2bf(silu_f(a));
                        }
                        af[kb] = __builtin_bit_cast(bf16x8, au);
                    }
                    float maskr[4];
                    #pragma unroll
                    for (int r = 0; r < 4; r++) {
                        int j2 = g*16 + quad*4 + r;        // D-frag row
                        float dd = s_d2[i*32 + j2];
                        maskr[r] = (dd < 1.0f && j2 != i) ? 1.0f : 0.0f;
                    }
                    #pragma unroll
                    for (int nt = 0; nt < 8; nt++) {
                        f32x4 acc = {0.f,0.f,0.f,0.f};
                        #pragma unroll
                        for (int kb = 0; kb < 4; kb++)
                            acc = __builtin_amdgcn_mfma_f32_16x16x32_bf16(af[kb], bfr[nt][kb], acc, 0, 0, 0);
                        #pragma unroll
                        for (int r = 0; r < 4; r++)
                            vsum[nt] += maskr[r] * silu_f(acc[r] + be2v[nt]);
                    }
                }
                #pragma unroll
                for (int nt = 0; nt < 8; nt++) {
                    float v = vsum[nt];
                    v += __shfl_xor(v, 16);
                    v += __shfl_xor(v, 32);
                    if (lane < 16) s_A2[i*136 + nt*16 + lane] = f2bf(v);  // agg (bf16 A-stage)
                }
            }
        }
        __syncthreads();

        // ---- u = silu(hg@Wh1a + agg@Wh1b + bh1) ----
        float uval[2][4];
        {
            const unsigned short* w1a = wt + (((size_t)l*6 + 3) << 14);
            const unsigned short* w1b = wt + (((size_t)l*6 + 4) << 14);
            int mt = w & 1, ng = w >> 1;
            #pragma unroll
            for (int t2 = 0; t2 < 2; t2++) {
                int nt = ng + t2*4, ncl = nt*16 + lm;
                f32x4 acc = {0.f,0.f,0.f,0.f};
                #pragma unroll
                for (int kb = 0; kb < 4; kb++) {
                    bf16x8 a  = *(const bf16x8*)&s_A1[(mt*16+lm)*136 + kb*32 + quad*8];
                    bf16x8 bb = *(const bf16x8*)&w1a[ncl*128 + kb*32 + quad*8];
                    acc = __builtin_amdgcn_mfma_f32_16x16x32_bf16(a, bb, acc, 0, 0, 0);
                }
                #pragma unroll
                for (int kb = 0; kb < 4; kb++) {
                    bf16x8 a  = *(const bf16x8*)&s_A2[(mt*16+lm)*136 + kb*32 + quad*8];
                    bf16x8 bb = *(const bf16x8*)&w1b[ncl*128 + kb*32 + quad*8];
                    acc = __builtin_amdgcn_mfma_f32_16x16x32_bf16(a, bb, acc, 0, 0, 0);
                }
                float bh = bh1[l*128 + ncl];
                #pragma unroll
                for (int r = 0; r < 4; r++) uval[t2][r] = silu_f(acc[r] + bh);
            }
        }
        __syncthreads();                                   // before overwriting A1 with u
        {
            int mt = w & 1, ng = w >> 1;
            #pragma unroll
            for (int t2 = 0; t2 < 2; t2++) {
                int nt = ng + t2*4;
                #pragma unroll
                for (int r = 0; r < 4; r++)
                    s_A1[(mt*16 + quad*4 + r)*136 + nt*16 + lm] = f2bf(uval[t2][r]);
            }
        }
        __syncthreads();

        // ---- hg += u@Wh2 + bh2 ----
        {
            const unsigned short* w2 = wt + (((size_t)l*6 + 5) << 14);
            int mt = w & 1, ng = w >> 1;
            #pragma unroll
            for (int t2 = 0; t2 < 2; t2++) {
                int nt = ng + t2*4, ncl = nt*16 + lm;
                f32x4 acc = {0.f,0.f,0.f,0.f};
                #pragma unroll
                for (int kb = 0; kb < 4; kb++) {
                    bf16x8 a  = *(const bf16x8*)&s_A1[(mt*16+lm)*136 + kb*32 + quad*8];
                    bf16x8 bb = *(const bf16x8*)&w2[ncl*128 + kb*32 + quad*8];
                    acc = __builtin_amdgcn_mfma_f32_16x16x32_bf16(a, bb, acc, 0, 0, 0);
                }
                float bh = bh2[l*128 + ncl];
                #pragma unroll
                for (int r = 0; r < 4; r++) {
                    int m = mt*16 + quad*4 + r;
                    s_hg[m*129 + ncl] += acc[r] + bh;
                }
            }
        }
        __syncthreads();
    }

    // ---- output head ----
    {
        int m = tid >> 4, c = (tid & 15) * 8;
        #pragma unroll
        for (int q = 0; q < 8; q++) s_A1[m*136 + c + q] = f2bf(s_hg[m*129 + c + q]);
    }
    __syncthreads();
    {   // ho = hg@W_out + b_out -> A2 (bf16)
        const unsigned short* wo = wt + ((size_t)12 << 14);
        int mt = w & 1, ng = w >> 1;
        #pragma unroll
        for (int t2 = 0; t2 < 2; t2++) {
            int nt = ng + t2*4, ncl = nt*16 + lm;
            f32x4 acc = {0.f,0.f,0.f,0.f};
            #pragma unroll
            for (int kb = 0; kb < 4; kb++) {
                bf16x8 a  = *(const bf16x8*)&s_A1[(mt*16+lm)*136 + kb*32 + quad*8];
                bf16x8 bb = *(const bf16x8*)&wo[ncl*128 + kb*32 + quad*8];
                acc = __builtin_amdgcn_mfma_f32_16x16x32_bf16(a, bb, acc, 0, 0, 0);
            }
            float bo = b_out[ncl];
            #pragma unroll
            for (int r = 0; r < 4; r++)
                s_A2[(mt*16 + quad*4 + r)*136 + ncl] = f2bf(acc[r] + bo);
        }
    }
    __syncthreads();
    float* s_g = (float*)s_mimj;                           // reuse (g is 32x129 fp32)
    {   // g = silu(ho@Wn1 + bn1) -> s_g fp32
        const unsigned short* wn1 = wt + ((size_t)13 << 14);
        int mt = w & 1, ng = w >> 1;
        #pragma unroll
        for (int t2 = 0; t2 < 2; t2++) {
            int nt = ng + t2*4, ncl = nt*16 + lm;
            f32x4 acc = {0.f,0.f,0.f,0.f};
            #pragma unroll
            for (int kb = 0; kb < 4; kb++) {
                bf16x8 a  = *(const bf16x8*)&s_A2[(mt*16+lm)*136 + kb*32 + quad*8];
                bf16x8 bb = *(const bf16x8*)&wn1[ncl*128 + kb*32 + quad*8];
                acc = __builtin_amdgcn_mfma_f32_16x16x32_bf16(a, bb, acc, 0, 0, 0);
            }
            float bn = bn1[ncl];
            #pragma unroll
            for (int r = 0; r < 4; r++)
                s_g[(mt*16 + quad*4 + r)*129 + ncl] = silu_f(acc[r] + bn);
        }
    }
    __syncthreads();
    // e = g @ Wn2 + bn2 ; out[b] = sum_m e[m]
    if (tid < 256) {
        int m = tid >> 3, s = tid & 7;
        float acc = 0.f;
        #pragma unroll
        for (int q = 0; q < 16; q++) {
            int hh = s*16 + q;
            acc += s_g[m*129 + hh] * Wn2[hh];
        }
        s_ep[tid] = acc;
    }
    __syncthreads();
    if (tid < 32) {
        float e = bn2[0];
        #pragma unroll
        for (int s = 0; s < 8; s++) e += s_ep[tid*8 + s];
        #pragma unroll
        for (int off = 16; off >= 1; off >>= 1) e += __shfl_down(e, off, 32);
        if (tid == 0) out[b] = e;
    }
}

extern "C" void kernel_launch(void* const* d_in, const int* in_sizes, int n_in,
                              void* d_out, int out_size, void* d_ws, size_t ws_size,
                              hipStream_t stream) {
    const float* h     = (const float*)d_in[0];
    const float* x     = (const float*)d_in[1];
    const float* W_in  = (const float*)d_in[3];
    const float* b_in  = (const float*)d_in[4];
    const float* We1   = (const float*)d_in[5];
    const float* be1   = (const float*)d_in[6];
    const float* We2   = (const float*)d_in[7];
    const float* be2   = (const float*)d_in[8];
    const float* Wh1   = (const float*)d_in[9];
    const float* bh1   = (const float*)d_in[10];
    const float* Wh2   = (const float*)d_in[11];
    const float* bh2   = (const float*)d_in[12];
    const float* W_out = (const float*)d_in[13];
    const float* b_out = (const float*)d_in[14];
    const float* Wn1   = (const float*)d_in[15];
    const float* bn1   = (const float*)d_in[16];
    const float* Wn2   = (const float*)d_in[17];
    const float* bn2   = (const float*)d_in[18];
    unsigned short* ws = (unsigned short*)d_ws;   // needs 14*16384*2 = 448 KB
    float* outp = (float*)d_out;

    prep_weights<<<896, 256, 0, stream>>>(We1, We2, Wh1, Wh2, W_out, Wn1, ws);
    sake_kernel<<<NB, 512, 0, stream>>>(h, x, W_in, b_in, We1, be1, be2, bh1, bh2,
                                        b_out, bn1, Wn2, bn2, ws, outp);
}

// Round 3
// 621.079 us; speedup vs baseline: 1.1099x; 1.1099x over previous
//
#include <hip/hip_runtime.h>
#include <hip/hip_bf16.h>

// SAKE GNN: B=512 graphs, M=32 atoms, H=128, L=2 layers, F_IN=16.
// Block = one graph, 512 threads (8 waves). All GEMMs via mfma_f32_16x16x32_bf16.
//
// R2 fix: R0/R1 spilled ~1.5 GB of scratch to HBM because the pair phase
// hoisted 128 VGPRs of We2^T fragments (+ ~50 live VGPRs) — the compiler
// lowered the fragment array to scratch regardless of __launch_bounds__.
// Now We2^T is staged into LDS (stride 136 shorts -> 2-way-conflict-free
// ds_read_b128) and B-frags are streamed per MFMA. Peak live regs ~50.

#define NB 512
#define NM 32
#define NH 128

typedef __bf16 bf16x8 __attribute__((ext_vector_type(8)));
typedef unsigned short u16x8 __attribute__((ext_vector_type(8)));
typedef float f32x4 __attribute__((ext_vector_type(4)));

__device__ __forceinline__ unsigned short f2bf(float f) {
    unsigned int u = __float_as_uint(f);
    u = u + 0x7FFFu + ((u >> 16) & 1u);   // RNE
    return (unsigned short)(u >> 16);
}
__device__ __forceinline__ float bf2f(unsigned short s) {
    return __uint_as_float(((unsigned int)s) << 16);
}
__device__ __forceinline__ float silu_f(float v) {
    return v / (1.0f + __expf(-v));
}

// ---------------- weight transpose+bf16 prep into workspace ----------------
// ws layout (each matrix 128x128 = 16384 bf16, stored as WT[n][k] = W[k][n]):
//   l*6 + {0:WaT, 1:WbT, 2:We2T, 3:Wh1aT, 4:Wh1bT, 5:Wh2T}, 12:W_outT, 13:Wn1T
__global__ void prep_weights(const float* __restrict__ We1, const float* __restrict__ We2,
                             const float* __restrict__ Wh1, const float* __restrict__ Wh2,
                             const float* __restrict__ W_out, const float* __restrict__ Wn1,
                             unsigned short* __restrict__ ws) {
    int gid = blockIdx.x * blockDim.x + threadIdx.x;
    if (gid >= 14 * 16384) return;
    int mtx = gid >> 14;
    int el  = gid & 16383;
    int n = el >> 7, k = el & 127;
    int l    = (mtx < 12) ? (mtx / 6) : 0;
    int kind = (mtx < 12) ? (mtx % 6) : (6 + (mtx - 12));
    float v = 0.f;
    switch (kind) {
        case 0: v = We1[(l*257 +       k)*128 + n]; break;   // Wa = We1[l, :128]
        case 1: v = We1[(l*257 + 128 + k)*128 + n]; break;   // Wb = We1[l, 128:256]
        case 2: v = We2[(l*128 +       k)*128 + n]; break;
        case 3: v = Wh1[(l*256 +       k)*128 + n]; break;   // Wh1a
        case 4: v = Wh1[(l*256 + 128 + k)*128 + n]; break;   // Wh1b
        case 5: v = Wh2[(l*128 +       k)*128 + n]; break;
        case 6: v = W_out[k*128 + n]; break;
        case 7: v = Wn1[k*128 + n]; break;
    }
    ws[gid] = f2bf(v);
}

// ---------------- main fused kernel ----------------
__global__ __launch_bounds__(512, 2) void sake_kernel(
    const float* __restrict__ h,   const float* __restrict__ x,
    const float* __restrict__ W_in,const float* __restrict__ b_in,
    const float* __restrict__ We1, const float* __restrict__ be1,
    const float* __restrict__ be2, const float* __restrict__ bh1,
    const float* __restrict__ bh2, const float* __restrict__ b_out,
    const float* __restrict__ bn1, const float* __restrict__ Wn2,
    const float* __restrict__ bn2, const unsigned short* __restrict__ wt,
    float* __restrict__ out)
{
    __shared__ __align__(16) float          s_d2[32*32];      // 4 KB
    __shared__ __align__(16) float          s_hg[32*129];     // 16.1 KB fp32 residual
    __shared__ __align__(16) unsigned short s_mimj[32*264];   // 16.5 KB bf16 (mi | mj+be1); reused as g fp32
    __shared__ __align__(16) unsigned short s_A1[32*136];     // 8.5 KB bf16 A-stage (hgb / ub)
    __shared__ __align__(16) unsigned short s_A2[32*136];     // 8.5 KB bf16 A-stage (agg / ho)
    __shared__ __align__(16) unsigned short s_we2[128*136];   // 34 KB We2^T, padded stride
    __shared__ __align__(16) float          s_wd[128];
    __shared__ __align__(16) float          s_x[32*4];
    __shared__ __align__(16) float          s_ep[256];

    const int tid  = threadIdx.x;
    const int b    = blockIdx.x;
    const int w    = tid >> 6;        // wave 0..7
    const int lane = tid & 63;
    const int quad = lane >> 4;
    const int lm   = lane & 15;

    // ---- load x, d2, hg = h@W_in + b_in ----
    if (tid < 32) {
        s_x[tid*4+0] = x[(b*32+tid)*3+0];
        s_x[tid*4+1] = x[(b*32+tid)*3+1];
        s_x[tid*4+2] = x[(b*32+tid)*3+2];
    }
    __syncthreads();
    for (int p = tid; p < 1024; p += 512) {
        int i = p >> 5, j = p & 31;
        float dx = s_x[i*4+0]-s_x[j*4+0];
        float dy = s_x[i*4+1]-s_x[j*4+1];
        float dz = s_x[i*4+2]-s_x[j*4+2];
        s_d2[p] = dx*dx + dy*dy + dz*dz;
    }
    {
        int k = tid & 127, mg = tid >> 7;   // mg 0..3 -> 8 rows each
        float wcol[16];
        #pragma unroll
        for (int f = 0; f < 16; f++) wcol[f] = W_in[f*128 + k];
        float bi = b_in[k];
        for (int rr = 0; rr < 8; rr++) {
            int m = mg*8 + rr;
            const float4* h4 = (const float4*)(h + (size_t)(b*32 + m)*16);
            float acc = bi;
            #pragma unroll
            for (int q = 0; q < 4; q++) {
                float4 hv = h4[q];
                acc += hv.x*wcol[q*4+0] + hv.y*wcol[q*4+1]
                     + hv.z*wcol[q*4+2] + hv.w*wcol[q*4+3];
            }
            s_hg[m*129 + k] = acc;
        }
    }
    __syncthreads();

    for (int l = 0; l < 2; l++) {
        // ---- stage hg -> bf16 A1, load wd, stage We2^T -> LDS ----
        {
            int m = tid >> 4, c = (tid & 15) * 8;
            #pragma unroll
            for (int q = 0; q < 8; q++) s_A1[m*136 + c + q] = f2bf(s_hg[m*129 + c + q]);
        }
        if (tid < 128) s_wd[tid] = We1[(l*257 + 256)*128 + tid];
        {   // 128 rows x 128 shorts; each thread copies 32 shorts (4x16B)
            const unsigned short* we2t = wt + (((size_t)l*6 + 2) << 14);
            int r = tid >> 2, part = tid & 3;
            const uint4* src = (const uint4*)(we2t + r*128 + part*32);
            uint4* dst = (uint4*)(&s_we2[r*136 + part*32]);
            dst[0] = src[0]; dst[1] = src[1]; dst[2] = src[2]; dst[3] = src[3];
        }
        __syncthreads();

        // ---- mi | mj GEMM: [32x128] @ [Wa | Wb] -> s_mimj (be1 folded into mj) ----
        {
            int mt = w & 1, ng = w >> 1;
            #pragma unroll
            for (int t4 = 0; t4 < 4; t4++) {
                int nt = ng + t4*4;                       // 0..15
                const unsigned short* bt = wt + (((size_t)l*6 + (nt < 8 ? 0 : 1)) << 14);
                int ncl = (nt & 7)*16 + lm;
                f32x4 acc = {0.f,0.f,0.f,0.f};
                #pragma unroll
                for (int kb = 0; kb < 4; kb++) {
                    bf16x8 a  = *(const bf16x8*)&s_A1[(mt*16+lm)*136 + kb*32 + quad*8];
                    bf16x8 bb = *(const bf16x8*)&bt[ncl*128 + kb*32 + quad*8];
                    acc = __builtin_amdgcn_mfma_f32_16x16x32_bf16(a, bb, acc, 0, 0, 0);
                }
                int c = nt*16 + lm;
                float bias = (nt >= 8) ? be1[l*128 + ncl] : 0.0f;
                #pragma unroll
                for (int r = 0; r < 4; r++)
                    s_mimj[(mt*16 + quad*4 + r)*264 + c] = f2bf(acc[r] + bias);
            }
        }
        __syncthreads();

        // ---- pair phase: silu1 -> (1024x128)@We2 -> silu2 -> mask -> agg ----
        {
            float be2v[8];
            #pragma unroll
            for (int nt = 0; nt < 8; nt++) be2v[nt] = be2[l*128 + nt*16 + lm];

            for (int ii = 0; ii < 4; ii++) {
                int i = ii*8 + w;                          // wave owns row i fully
                float vsum[8] = {0.f,0.f,0.f,0.f,0.f,0.f,0.f,0.f};
                #pragma unroll
                for (int g = 0; g < 2; g++) {
                    int j = g*16 + lm;
                    float d2v = s_d2[i*32 + j];
                    bf16x8 af[4];
                    #pragma unroll
                    for (int kb = 0; kb < 4; kb++) {
                        u16x8 miv = *(const u16x8*)&s_mimj[i*264 +       kb*32 + quad*8];
                        u16x8 mjv = *(const u16x8*)&s_mimj[j*264 + 128 + kb*32 + quad*8];
                        const float4* wd4 = (const float4*)&s_wd[kb*32 + quad*8];
                        float4 w0 = wd4[0], w1 = wd4[1];
                        float wdv[8] = {w0.x,w0.y,w0.z,w0.w,w1.x,w1.y,w1.z,w1.w};
                        u16x8 au;
                        #pragma unroll
                        for (int jj = 0; jj < 8; jj++) {
                            float a = bf2f(miv[jj]) + bf2f(mjv[jj]) + d2v*wdv[jj];
                            au[jj] = f2bf(silu_f(a));
                        }
                        af[kb] = __builtin_bit_cast(bf16x8, au);
                    }
                    float maskr[4];
                    #pragma unroll
                    for (int r = 0; r < 4; r++) {
                        int j2 = g*16 + quad*4 + r;        // D-frag row
                        float dd = s_d2[i*32 + j2];
                        maskr[r] = (dd < 1.0f && j2 != i) ? 1.0f : 0.0f;
                    }
                    #pragma unroll
                    for (int nt = 0; nt < 8; nt++) {
                        const unsigned short* bp = &s_we2[(nt*16+lm)*136 + quad*8];
                        f32x4 acc = {0.f,0.f,0.f,0.f};
                        #pragma unroll
                        for (int kb = 0; kb < 4; kb++) {
                            bf16x8 bb = *(const bf16x8*)(bp + kb*32);
                            acc = __builtin_amdgcn_mfma_f32_16x16x32_bf16(af[kb], bb, acc, 0, 0, 0);
                        }
                        #pragma unroll
                        for (int r = 0; r < 4; r++)
                            vsum[nt] += maskr[r] * silu_f(acc[r] + be2v[nt]);
                    }
                }
                #pragma unroll
                for (int nt = 0; nt < 8; nt++) {
                    float v = vsum[nt];
                    v += __shfl_xor(v, 16);
                    v += __shfl_xor(v, 32);
                    if (lane < 16) s_A2[i*136 + nt*16 + lane] = f2bf(v);  // agg (bf16 A-stage)
                }
            }
        }
        __syncthreads();

        // ---- u = silu(hg@Wh1a + agg@Wh1b + bh1) ----
        float uval[2][4];
        {
            const unsigned short* w1a = wt + (((size_t)l*6 + 3) << 14);
            const unsigned short* w1b = wt + (((size_t)l*6 + 4) << 14);
            int mt = w & 1, ng = w >> 1;
            #pragma unroll
            for (int t2 = 0; t2 < 2; t2++) {
                int nt = ng + t2*4, ncl = nt*16 + lm;
                f32x4 acc = {0.f,0.f,0.f,0.f};
                #pragma unroll
                for (int kb = 0; kb < 4; kb++) {
                    bf16x8 a  = *(const bf16x8*)&s_A1[(mt*16+lm)*136 + kb*32 + quad*8];
                    bf16x8 bb = *(const bf16x8*)&w1a[ncl*128 + kb*32 + quad*8];
                    acc = __builtin_amdgcn_mfma_f32_16x16x32_bf16(a, bb, acc, 0, 0, 0);
                }
                #pragma unroll
                for (int kb = 0; kb < 4; kb++) {
                    bf16x8 a  = *(const bf16x8*)&s_A2[(mt*16+lm)*136 + kb*32 + quad*8];
                    bf16x8 bb = *(const bf16x8*)&w1b[ncl*128 + kb*32 + quad*8];
                    acc = __builtin_amdgcn_mfma_f32_16x16x32_bf16(a, bb, acc, 0, 0, 0);
                }
                float bh = bh1[l*128 + ncl];
                #pragma unroll
                for (int r = 0; r < 4; r++) uval[t2][r] = silu_f(acc[r] + bh);
            }
        }
        __syncthreads();                                   // before overwriting A1 with u
        {
            int mt = w & 1, ng = w >> 1;
            #pragma unroll
            for (int t2 = 0; t2 < 2; t2++) {
                int nt = ng + t2*4;
                #pragma unroll
                for (int r = 0; r < 4; r++)
                    s_A1[(mt*16 + quad*4 + r)*136 + nt*16 + lm] = f2bf(uval[t2][r]);
            }
        }
        __syncthreads();

        // ---- hg += u@Wh2 + bh2 ----
        {
            const unsigned short* w2 = wt + (((size_t)l*6 + 5) << 14);
            int mt = w & 1, ng = w >> 1;
            #pragma unroll
            for (int t2 = 0; t2 < 2; t2++) {
                int nt = ng + t2*4, ncl = nt*16 + lm;
                f32x4 acc = {0.f,0.f,0.f,0.f};
                #pragma unroll
                for (int kb = 0; kb < 4; kb++) {
                    bf16x8 a  = *(const bf16x8*)&s_A1[(mt*16+lm)*136 + kb*32 + quad*8];
                    bf16x8 bb = *(const bf16x8*)&w2[ncl*128 + kb*32 + quad*8];
                    acc = __builtin_amdgcn_mfma_f32_16x16x32_bf16(a, bb, acc, 0, 0, 0);
                }
                float bh = bh2[l*128 + ncl];
                #pragma unroll
                for (int r = 0; r < 4; r++) {
                    int m = mt*16 + quad*4 + r;
                    s_hg[m*129 + ncl] += acc[r] + bh;
                }
            }
        }
        __syncthreads();
    }

    // ---- output head ----
    {
        int m = tid >> 4, c = (tid & 15) * 8;
        #pragma unroll
        for (int q = 0; q < 8; q++) s_A1[m*136 + c + q] = f2bf(s_hg[m*129 + c + q]);
    }
    __syncthreads();
    {   // ho = hg@W_out + b_out -> A2 (bf16)
        const unsigned short* wo = wt + ((size_t)12 << 14);
        int mt = w & 1, ng = w >> 1;
        #pragma unroll
        for (int t2 = 0; t2 < 2; t2++) {
            int nt = ng + t2*4, ncl = nt*16 + lm;
            f32x4 acc = {0.f,0.f,0.f,0.f};
            #pragma unroll
            for (int kb = 0; kb < 4; kb++) {
                bf16x8 a  = *(const bf16x8*)&s_A1[(mt*16+lm)*136 + kb*32 + quad*8];
                bf16x8 bb = *(const bf16x8*)&wo[ncl*128 + kb*32 + quad*8];
                acc = __builtin_amdgcn_mfma_f32_16x16x32_bf16(a, bb, acc, 0, 0, 0);
            }
            float bo = b_out[ncl];
            #pragma unroll
            for (int r = 0; r < 4; r++)
                s_A2[(mt*16 + quad*4 + r)*136 + ncl] = f2bf(acc[r] + bo);
        }
    }
    __syncthreads();
    float* s_g = (float*)s_mimj;                           // reuse (g is 32x129 fp32)
    {   // g = silu(ho@Wn1 + bn1) -> s_g fp32
        const unsigned short* wn1 = wt + ((size_t)13 << 14);
        int mt = w & 1, ng = w >> 1;
        #pragma unroll
        for (int t2 = 0; t2 < 2; t2++) {
            int nt = ng + t2*4, ncl = nt*16 + lm;
            f32x4 acc = {0.f,0.f,0.f,0.f};
            #pragma unroll
            for (int kb = 0; kb < 4; kb++) {
                bf16x8 a  = *(const bf16x8*)&s_A2[(mt*16+lm)*136 + kb*32 + quad*8];
                bf16x8 bb = *(const bf16x8*)&wn1[ncl*128 + kb*32 + quad*8];
                acc = __builtin_amdgcn_mfma_f32_16x16x32_bf16(a, bb, acc, 0, 0, 0);
            }
            float bn = bn1[ncl];
            #pragma unroll
            for (int r = 0; r < 4; r++)
                s_g[(mt*16 + quad*4 + r)*129 + ncl] = silu_f(acc[r] + bn);
        }
    }
    __syncthreads();
    // e = g @ Wn2 + bn2 ; out[b] = sum_m e[m]
    if (tid < 256) {
        int m = tid >> 3, s = tid & 7;
        float acc = 0.f;
        #pragma unroll
        for (int q = 0; q < 16; q++) {
            int hh = s*16 + q;
            acc += s_g[m*129 + hh] * Wn2[hh];
        }
        s_ep[tid] = acc;
    }
    __syncthreads();
    if (tid < 32) {
        float e = bn2[0];
        #pragma unroll
        for (int s = 0; s < 8; s++) e += s_ep[tid*8 + s];
        #pragma unroll
        for (int off = 16; off >= 1; off >>= 1) e += __shfl_down(e, off, 32);
        if (tid == 0) out[b] = e;
    }
}

extern "C" void kernel_launch(void* const* d_in, const int* in_sizes, int n_in,
                              void* d_out, int out_size, void* d_ws, size_t ws_size,
                              hipStream_t stream) {
    const float* h     = (const float*)d_in[0];
    const float* x     = (const float*)d_in[1];
    const float* W_in  = (const float*)d_in[3];
    const float* b_in  = (const float*)d_in[4];
    const float* We1   = (const float*)d_in[5];
    const float* be1   = (const float*)d_in[6];
    const float* We2   = (const float*)d_in[7];
    const float* be2   = (const float*)d_in[8];
    const float* Wh1   = (const float*)d_in[9];
    const float* bh1   = (const float*)d_in[10];
    const float* Wh2   = (const float*)d_in[11];
    const float* bh2   = (const float*)d_in[12];
    const float* W_out = (const float*)d_in[13];
    const float* b_out = (const float*)d_in[14];
    const float* Wn1   = (const float*)d_in[15];
    const float* bn1   = (const float*)d_in[16];
    const float* Wn2   = (const float*)d_in[17];
    const float* bn2   = (const float*)d_in[18];
    unsigned short* ws = (unsigned short*)d_ws;   // needs 14*16384*2 = 448 KB
    float* outp = (float*)d_out;

    prep_weights<<<896, 256, 0, stream>>>(We1, We2, Wh1, Wh2, W_out, Wn1, ws);
    sake_kernel<<<NB, 512, 0, stream>>>(h, x, W_in, b_in, We1, be1, be2, bh1, bh2,
                                        b_out, bn1, Wn2, bn2, ws, outp);
}

// Round 4
// 398.446 us; speedup vs baseline: 1.7300x; 1.5588x over previous
//
#include <hip/hip_runtime.h>
#include <hip/hip_bf16.h>

// SAKE GNN: B=512 graphs, M=32 atoms, H=128, L=2 layers, F_IN=16.
// Block = one graph, 512 threads (8 waves). All GEMMs via mfma_f32_16x16x32_bf16.
//
// R3 diagnosis: 1.3 GB/dispatch HBM traffic = private arrays (vsum[nt],
// af[kb], per-element vector subscripts) lowered to SCRATCH when the
// compiler declines to fully unroll the big pair-loop bodies. 1.7 KB/thread
// dynamic scratch x 262K threads matches WRITE_SIZE=455 MB exactly.
// R4 fix: hand-stamped named scalars everywhere in hot paths — zero
// indexable private storage left. bf16 pairs decoded via uint4 fields.

#define NB 512

typedef __bf16 bf16x8 __attribute__((ext_vector_type(8)));
typedef float f32x4 __attribute__((ext_vector_type(4)));

__device__ __forceinline__ unsigned short f2bf(float f) {
    unsigned int u = __float_as_uint(f);
    u = u + 0x7FFFu + ((u >> 16) & 1u);   // RNE
    return (unsigned short)(u >> 16);
}
__device__ __forceinline__ unsigned int packbf(float lo, float hi) {
    return (unsigned int)f2bf(lo) | ((unsigned int)f2bf(hi) << 16);
}
__device__ __forceinline__ float bflo(unsigned int u) { return __uint_as_float(u << 16); }
__device__ __forceinline__ float bfhi(unsigned int u) { return __uint_as_float(u & 0xffff0000u); }
__device__ __forceinline__ float silu_f(float v) { return v / (1.0f + __expf(-v)); }

// ---------------- weight transpose+bf16 prep into workspace ----------------
// ws layout (each matrix 128x128 = 16384 bf16, stored as WT[n][k] = W[k][n]):
//   l*6 + {0:WaT, 1:WbT, 2:We2T, 3:Wh1aT, 4:Wh1bT, 5:Wh2T}, 12:W_outT, 13:Wn1T
__global__ void prep_weights(const float* __restrict__ We1, const float* __restrict__ We2,
                             const float* __restrict__ Wh1, const float* __restrict__ Wh2,
                             const float* __restrict__ W_out, const float* __restrict__ Wn1,
                             unsigned short* __restrict__ ws) {
    int gid = blockIdx.x * blockDim.x + threadIdx.x;
    if (gid >= 14 * 16384) return;
    int mtx = gid >> 14;
    int el  = gid & 16383;
    int n = el >> 7, k = el & 127;
    int l    = (mtx < 12) ? (mtx / 6) : 0;
    int kind = (mtx < 12) ? (mtx % 6) : (6 + (mtx - 12));
    float v = 0.f;
    switch (kind) {
        case 0: v = We1[(l*257 +       k)*128 + n]; break;   // Wa = We1[l, :128]
        case 1: v = We1[(l*257 + 128 + k)*128 + n]; break;   // Wb = We1[l, 128:256]
        case 2: v = We2[(l*128 +       k)*128 + n]; break;
        case 3: v = Wh1[(l*256 +       k)*128 + n]; break;   // Wh1a
        case 4: v = Wh1[(l*256 + 128 + k)*128 + n]; break;   // Wh1b
        case 5: v = Wh2[(l*128 +       k)*128 + n]; break;
        case 6: v = W_out[k*128 + n]; break;
        case 7: v = Wn1[k*128 + n]; break;
    }
    ws[gid] = f2bf(v);
}

#define MFMA16(ACC, A, B) (ACC) = __builtin_amdgcn_mfma_f32_16x16x32_bf16((A), (B), (ACC), 0, 0, 0)

// ---------------- main fused kernel ----------------
__global__ __launch_bounds__(512, 2) void sake_kernel(
    const float* __restrict__ h,   const float* __restrict__ x,
    const float* __restrict__ W_in,const float* __restrict__ b_in,
    const float* __restrict__ We1, const float* __restrict__ be1,
    const float* __restrict__ be2, const float* __restrict__ bh1,
    const float* __restrict__ bh2, const float* __restrict__ b_out,
    const float* __restrict__ bn1, const float* __restrict__ Wn2,
    const float* __restrict__ bn2, const unsigned short* __restrict__ wt,
    float* __restrict__ out)
{
    __shared__ __align__(16) float          s_d2[32*32];      // 4 KB
    __shared__ __align__(16) float          s_hg[32*129];     // 16.1 KB fp32 residual
    __shared__ __align__(16) unsigned short s_mimj[32*264];   // 16.9 KB (mi|mj+be1); reused: u-stage / g fp32
    __shared__ __align__(16) unsigned short s_A1[32*136];     // 8.5 KB bf16 A-stage (hgb)
    __shared__ __align__(16) unsigned short s_A2[32*136];     // 8.5 KB bf16 A-stage (agg / ho)
    __shared__ __align__(16) unsigned short s_we2[128*136];   // 34 KB We2^T, padded stride
    __shared__ __align__(16) float          s_wd[128];
    __shared__ __align__(16) float          s_x[32*4];
    __shared__ __align__(16) float          s_ep[256];

    const int tid  = threadIdx.x;
    const int b    = blockIdx.x;
    const int w    = tid >> 6;        // wave 0..7
    const int lane = tid & 63;
    const int quad = lane >> 4;
    const int lm   = lane & 15;
    const int mt   = w & 1;           // row-half for 32-row GEMMs
    const int ng   = w >> 1;          // col-tile group

    // ---- load x, d2, hg = h@W_in + b_in ----
    if (tid < 32) {
        s_x[tid*4+0] = x[(b*32+tid)*3+0];
        s_x[tid*4+1] = x[(b*32+tid)*3+1];
        s_x[tid*4+2] = x[(b*32+tid)*3+2];
    }
    __syncthreads();
    for (int p = tid; p < 1024; p += 512) {
        int i = p >> 5, j = p & 31;
        float dx = s_x[i*4+0]-s_x[j*4+0];
        float dy = s_x[i*4+1]-s_x[j*4+1];
        float dz = s_x[i*4+2]-s_x[j*4+2];
        s_d2[p] = dx*dx + dy*dy + dz*dz;
    }
    {
        int k = tid & 127, mg = tid >> 7;   // mg 0..3 -> 8 rows each
        float c0 = W_in[       k], c1 = W_in[ 128+k], c2 = W_in[ 256+k], c3 = W_in[ 384+k];
        float c4 = W_in[ 512+k], c5 = W_in[ 640+k], c6 = W_in[ 768+k], c7 = W_in[ 896+k];
        float c8 = W_in[1024+k], c9 = W_in[1152+k], c10= W_in[1280+k], c11= W_in[1408+k];
        float c12= W_in[1536+k], c13= W_in[1664+k], c14= W_in[1792+k], c15= W_in[1920+k];
        float bi = b_in[k];
        for (int rr = 0; rr < 8; rr++) {
            int m = mg*8 + rr;
            const float4* h4 = (const float4*)(h + (size_t)(b*32 + m)*16);
            float4 h0 = h4[0], h1 = h4[1], h2 = h4[2], h3 = h4[3];
            float acc = bi
                + h0.x*c0  + h0.y*c1  + h0.z*c2  + h0.w*c3
                + h1.x*c4  + h1.y*c5  + h1.z*c6  + h1.w*c7
                + h2.x*c8  + h2.y*c9  + h2.z*c10 + h2.w*c11
                + h3.x*c12 + h3.y*c13 + h3.z*c14 + h3.w*c15;
            s_hg[m*129 + k] = acc;
        }
    }
    __syncthreads();

    for (int l = 0; l < 2; l++) {
        // ---- stage hg -> bf16 A1, load wd, stage We2^T -> LDS ----
        {
            int m = tid >> 4, c = (tid & 15) * 8;
            #pragma unroll
            for (int q = 0; q < 8; q++) s_A1[m*136 + c + q] = f2bf(s_hg[m*129 + c + q]);
        }
        if (tid < 128) s_wd[tid] = We1[(l*257 + 256)*128 + tid];
        {   // 128 rows x 128 shorts; each thread copies 64 B
            const unsigned short* we2t = wt + (((size_t)l*6 + 2) << 14);
            int r = tid >> 2, part = tid & 3;
            const uint4* src = (const uint4*)(we2t + r*128 + part*32);
            uint4* dst = (uint4*)(&s_we2[r*136 + part*32]);
            dst[0] = src[0]; dst[1] = src[1]; dst[2] = src[2]; dst[3] = src[3];
        }
        __syncthreads();

        // ---- mi | mj GEMM: [32x128] @ [Wa | Wb] -> s_mimj (be1 folded into mj) ----
        for (int t4 = 0; t4 < 4; t4++) {
            int nt = ng + t4*4;                       // 0..15
            const unsigned short* bt = wt + (((size_t)l*6 + (nt < 8 ? 0 : 1)) << 14);
            int ncl = (nt & 7)*16 + lm;
            f32x4 acc = {0.f,0.f,0.f,0.f};
            #pragma unroll
            for (int kb = 0; kb < 4; kb++) {
                bf16x8 a  = *(const bf16x8*)&s_A1[(mt*16+lm)*136 + kb*32 + quad*8];
                bf16x8 bb = *(const bf16x8*)&bt[ncl*128 + kb*32 + quad*8];
                MFMA16(acc, a, bb);
            }
            int c = nt*16 + lm;
            float bias = (nt >= 8) ? be1[l*128 + ncl] : 0.0f;
            s_mimj[(mt*16 + quad*4 + 0)*264 + c] = f2bf(acc.x + bias);
            s_mimj[(mt*16 + quad*4 + 1)*264 + c] = f2bf(acc.y + bias);
            s_mimj[(mt*16 + quad*4 + 2)*264 + c] = f2bf(acc.z + bias);
            s_mimj[(mt*16 + quad*4 + 3)*264 + c] = f2bf(acc.w + bias);
        }
        __syncthreads();

        // ---- pair phase: silu1 -> (1024x128)@We2 -> silu2 -> mask -> agg ----
        {
            const float be2_0 = be2[l*128 +   0 + lm], be2_1 = be2[l*128 +  16 + lm];
            const float be2_2 = be2[l*128 +  32 + lm], be2_3 = be2[l*128 +  48 + lm];
            const float be2_4 = be2[l*128 +  64 + lm], be2_5 = be2[l*128 +  80 + lm];
            const float be2_6 = be2[l*128 +  96 + lm], be2_7 = be2[l*128 + 112 + lm];

            for (int ii = 0; ii < 4; ii++) {
                const int i = ii*8 + w;               // wave owns row i fully
                float vs0=0.f,vs1=0.f,vs2=0.f,vs3=0.f,vs4=0.f,vs5=0.f,vs6=0.f,vs7=0.f;
                #pragma unroll
                for (int g = 0; g < 2; g++) {
                    const int j = g*16 + lm;
                    const float d2v = s_d2[i*32 + j];
                    bf16x8 af0, af1, af2, af3;
#define MAKE_AF(KB, AF) { \
    const uint4 miu = *(const uint4*)&s_mimj[i*264 + (KB)*32 + quad*8]; \
    const uint4 mju = *(const uint4*)&s_mimj[j*264 + 128 + (KB)*32 + quad*8]; \
    const float4 wa = *(const float4*)&s_wd[(KB)*32 + quad*8]; \
    const float4 wb = *(const float4*)&s_wd[(KB)*32 + quad*8 + 4]; \
    uint4 au; \
    au.x = packbf(silu_f(bflo(miu.x)+bflo(mju.x)+d2v*wa.x), silu_f(bfhi(miu.x)+bfhi(mju.x)+d2v*wa.y)); \
    au.y = packbf(silu_f(bflo(miu.y)+bflo(mju.y)+d2v*wa.z), silu_f(bfhi(miu.y)+bfhi(mju.y)+d2v*wa.w)); \
    au.z = packbf(silu_f(bflo(miu.z)+bflo(mju.z)+d2v*wb.x), silu_f(bfhi(miu.z)+bfhi(mju.z)+d2v*wb.y)); \
    au.w = packbf(silu_f(bflo(miu.w)+bflo(mju.w)+d2v*wb.z), silu_f(bfhi(miu.w)+bfhi(mju.w)+d2v*wb.w)); \
    AF = __builtin_bit_cast(bf16x8, au); }
                    MAKE_AF(0, af0) MAKE_AF(1, af1) MAKE_AF(2, af2) MAKE_AF(3, af3)
#undef MAKE_AF
                    const int jb = g*16 + quad*4;
                    const float mk0 = (s_d2[i*32 + jb + 0] < 1.0f && (jb+0) != i) ? 1.f : 0.f;
                    const float mk1 = (s_d2[i*32 + jb + 1] < 1.0f && (jb+1) != i) ? 1.f : 0.f;
                    const float mk2 = (s_d2[i*32 + jb + 2] < 1.0f && (jb+2) != i) ? 1.f : 0.f;
                    const float mk3 = (s_d2[i*32 + jb + 3] < 1.0f && (jb+3) != i) ? 1.f : 0.f;
#define NT_BODY(NT, VS) { \
    const unsigned short* bp = &s_we2[((NT)*16+lm)*136 + quad*8]; \
    f32x4 acc = {0.f,0.f,0.f,0.f}; \
    MFMA16(acc, af0, *(const bf16x8*)(bp      )); \
    MFMA16(acc, af1, *(const bf16x8*)(bp +  32)); \
    MFMA16(acc, af2, *(const bf16x8*)(bp +  64)); \
    MFMA16(acc, af3, *(const bf16x8*)(bp +  96)); \
    VS += mk0*silu_f(acc.x + be2_##NT) + mk1*silu_f(acc.y + be2_##NT) \
        + mk2*silu_f(acc.z + be2_##NT) + mk3*silu_f(acc.w + be2_##NT); }
                    NT_BODY(0, vs0) NT_BODY(1, vs1) NT_BODY(2, vs2) NT_BODY(3, vs3)
                    NT_BODY(4, vs4) NT_BODY(5, vs5) NT_BODY(6, vs6) NT_BODY(7, vs7)
#undef NT_BODY
                }
#define RED(NT, VS) { float v = VS; v += __shfl_xor(v, 16); v += __shfl_xor(v, 32); \
    if (lane < 16) s_A2[i*136 + (NT)*16 + lane] = f2bf(v); }
                RED(0, vs0) RED(1, vs1) RED(2, vs2) RED(3, vs3)
                RED(4, vs4) RED(5, vs5) RED(6, vs6) RED(7, vs7)
#undef RED
            }
        }
        __syncthreads();

        // ---- u = silu(hg@Wh1a + agg@Wh1b + bh1) -> s_u (reuses s_mimj, stride 136) ----
        unsigned short* s_u = s_mimj;
        {
            const unsigned short* w1a = wt + (((size_t)l*6 + 3) << 14);
            const unsigned short* w1b = wt + (((size_t)l*6 + 4) << 14);
#define U_GEMM(T2) { \
    const int nt = ng + (T2)*4, ncl = nt*16 + lm; \
    f32x4 acc = {0.f,0.f,0.f,0.f}; \
    _Pragma("unroll") \
    for (int kb = 0; kb < 4; kb++) { \
        bf16x8 a  = *(const bf16x8*)&s_A1[(mt*16+lm)*136 + kb*32 + quad*8]; \
        bf16x8 bb = *(const bf16x8*)&w1a[ncl*128 + kb*32 + quad*8]; \
        MFMA16(acc, a, bb); } \
    _Pragma("unroll") \
    for (int kb = 0; kb < 4; kb++) { \
        bf16x8 a  = *(const bf16x8*)&s_A2[(mt*16+lm)*136 + kb*32 + quad*8]; \
        bf16x8 bb = *(const bf16x8*)&w1b[ncl*128 + kb*32 + quad*8]; \
        MFMA16(acc, a, bb); } \
    const float bh = bh1[l*128 + ncl]; \
    s_u[(mt*16 + quad*4 + 0)*136 + ncl] = f2bf(silu_f(acc.x + bh)); \
    s_u[(mt*16 + quad*4 + 1)*136 + ncl] = f2bf(silu_f(acc.y + bh)); \
    s_u[(mt*16 + quad*4 + 2)*136 + ncl] = f2bf(silu_f(acc.z + bh)); \
    s_u[(mt*16 + quad*4 + 3)*136 + ncl] = f2bf(silu_f(acc.w + bh)); }
            U_GEMM(0) U_GEMM(1)
#undef U_GEMM
        }
        __syncthreads();

        // ---- hg += u@Wh2 + bh2 ----
        {
            const unsigned short* w2 = wt + (((size_t)l*6 + 5) << 14);
#define H_GEMM(T2) { \
    const int nt = ng + (T2)*4, ncl = nt*16 + lm; \
    f32x4 acc = {0.f,0.f,0.f,0.f}; \
    _Pragma("unroll") \
    for (int kb = 0; kb < 4; kb++) { \
        bf16x8 a  = *(const bf16x8*)&s_u[(mt*16+lm)*136 + kb*32 + quad*8]; \
        bf16x8 bb = *(const bf16x8*)&w2[ncl*128 + kb*32 + quad*8]; \
        MFMA16(acc, a, bb); } \
    const float bh = bh2[l*128 + ncl]; \
    s_hg[(mt*16 + quad*4 + 0)*129 + ncl] += acc.x + bh; \
    s_hg[(mt*16 + quad*4 + 1)*129 + ncl] += acc.y + bh; \
    s_hg[(mt*16 + quad*4 + 2)*129 + ncl] += acc.z + bh; \
    s_hg[(mt*16 + quad*4 + 3)*129 + ncl] += acc.w + bh; }
            H_GEMM(0) H_GEMM(1)
#undef H_GEMM
        }
        __syncthreads();
    }

    // ---- output head ----
    {
        int m = tid >> 4, c = (tid & 15) * 8;
        #pragma unroll
        for (int q = 0; q < 8; q++) s_A1[m*136 + c + q] = f2bf(s_hg[m*129 + c + q]);
    }
    __syncthreads();
    {   // ho = hg@W_out + b_out -> A2 (bf16)
        const unsigned short* wo = wt + ((size_t)12 << 14);
#define O_GEMM(T2) { \
    const int nt = ng + (T2)*4, ncl = nt*16 + lm; \
    f32x4 acc = {0.f,0.f,0.f,0.f}; \
    _Pragma("unroll") \
    for (int kb = 0; kb < 4; kb++) { \
        bf16x8 a  = *(const bf16x8*)&s_A1[(mt*16+lm)*136 + kb*32 + quad*8]; \
        bf16x8 bb = *(const bf16x8*)&wo[ncl*128 + kb*32 + quad*8]; \
        MFMA16(acc, a, bb); } \
    const float bo = b_out[ncl]; \
    s_A2[(mt*16 + quad*4 + 0)*136 + ncl] = f2bf(acc.x + bo); \
    s_A2[(mt*16 + quad*4 + 1)*136 + ncl] = f2bf(acc.y + bo); \
    s_A2[(mt*16 + quad*4 + 2)*136 + ncl] = f2bf(acc.z + bo); \
    s_A2[(mt*16 + quad*4 + 3)*136 + ncl] = f2bf(acc.w + bo); }
        O_GEMM(0) O_GEMM(1)
#undef O_GEMM
    }
    __syncthreads();
    float* s_g = (float*)s_mimj;                           // reuse (g is 32x129 fp32)
    {   // g = silu(ho@Wn1 + bn1) -> s_g fp32
        const unsigned short* wn1 = wt + ((size_t)13 << 14);
#define G_GEMM(T2) { \
    const int nt = ng + (T2)*4, ncl = nt*16 + lm; \
    f32x4 acc = {0.f,0.f,0.f,0.f}; \
    _Pragma("unroll") \
    for (int kb = 0; kb < 4; kb++) { \
        bf16x8 a  = *(const bf16x8*)&s_A2[(mt*16+lm)*136 + kb*32 + quad*8]; \
        bf16x8 bb = *(const bf16x8*)&wn1[ncl*128 + kb*32 + quad*8]; \
        MFMA16(acc, a, bb); } \
    const float bn = bn1[ncl]; \
    s_g[(mt*16 + quad*4 + 0)*129 + ncl] = silu_f(acc.x + bn); \
    s_g[(mt*16 + quad*4 + 1)*129 + ncl] = silu_f(acc.y + bn); \
    s_g[(mt*16 + quad*4 + 2)*129 + ncl] = silu_f(acc.z + bn); \
    s_g[(mt*16 + quad*4 + 3)*129 + ncl] = silu_f(acc.w + bn); }
        G_GEMM(0) G_GEMM(1)
#undef G_GEMM
    }
    __syncthreads();
    // e = g @ Wn2 + bn2 ; out[b] = sum_m e[m]
    if (tid < 256) {
        int m = tid >> 3, s = tid & 7;
        float acc = 0.f;
        #pragma unroll
        for (int q = 0; q < 16; q++) {
            int hh = s*16 + q;
            acc += s_g[m*129 + hh] * Wn2[hh];
        }
        s_ep[tid] = acc;
    }
    __syncthreads();
    if (tid < 32) {
        float e = bn2[0];
        #pragma unroll
        for (int s = 0; s < 8; s++) e += s_ep[tid*8 + s];
        #pragma unroll
        for (int off = 16; off >= 1; off >>= 1) e += __shfl_down(e, off, 32);
        if (tid == 0) out[b] = e;
    }
}

extern "C" void kernel_launch(void* const* d_in, const int* in_sizes, int n_in,
                              void* d_out, int out_size, void* d_ws, size_t ws_size,
                              hipStream_t stream) {
    const float* h     = (const float*)d_in[0];
    const float* x     = (const float*)d_in[1];
    const float* W_in  = (const float*)d_in[3];
    const float* b_in  = (const float*)d_in[4];
    const float* We1   = (const float*)d_in[5];
    const float* be1   = (const float*)d_in[6];
    const float* We2   = (const float*)d_in[7];
    const float* be2   = (const float*)d_in[8];
    const float* Wh1   = (const float*)d_in[9];
    const float* bh1   = (const float*)d_in[10];
    const float* Wh2   = (const float*)d_in[11];
    const float* bh2   = (const float*)d_in[12];
    const float* W_out = (const float*)d_in[13];
    const float* b_out = (const float*)d_in[14];
    const float* Wn1   = (const float*)d_in[15];
    const float* bn1   = (const float*)d_in[16];
    const float* Wn2   = (const float*)d_in[17];
    const float* bn2   = (const float*)d_in[18];
    unsigned short* ws = (unsigned short*)d_ws;   // needs 14*16384*2 = 448 KB
    float* outp = (float*)d_out;

    prep_weights<<<896, 256, 0, stream>>>(We1, We2, Wh1, Wh2, W_out, Wn1, ws);
    sake_kernel<<<NB, 512, 0, stream>>>(h, x, W_in, b_in, We1, be1, be2, bh1, bh2,
                                        b_out, bn1, Wn2, bn2, ws, outp);
}

// Round 5
// 344.259 us; speedup vs baseline: 2.0023x; 1.1574x over previous
//
#include <hip/hip_runtime.h>
#include <hip/hip_bf16.h>

// SAKE GNN: B=512 graphs, M=32 atoms, H=128, L=2 layers, F_IN=16.
// Block = one graph, 512 threads (8 waves). All GEMMs via mfma_f32_16x16x32_bf16.
//
// R4 left 190 MB WRITE / 180 MB FETCH of residual scratch: the fully-unrolled
// pair-loop body (2 g-iters x [8 uint4 + 8 float4 LDS loads + 4 af frags])
// lets the scheduler hoist >128 live regs -> allocator spills at the 128-VGPR
// cap. R5: #pragma unroll 1 on the ii and g loops (no cross-iter hoisting),
// mi loads (i-dependent) hoisted out of the g loop as packed uint4s.

#define NB 512

typedef __bf16 bf16x8 __attribute__((ext_vector_type(8)));
typedef float f32x4 __attribute__((ext_vector_type(4)));

__device__ __forceinline__ unsigned short f2bf(float f) {
    unsigned int u = __float_as_uint(f);
    u = u + 0x7FFFu + ((u >> 16) & 1u);   // RNE
    return (unsigned short)(u >> 16);
}
__device__ __forceinline__ unsigned int packbf(float lo, float hi) {
    return (unsigned int)f2bf(lo) | ((unsigned int)f2bf(hi) << 16);
}
__device__ __forceinline__ float bflo(unsigned int u) { return __uint_as_float(u << 16); }
__device__ __forceinline__ float bfhi(unsigned int u) { return __uint_as_float(u & 0xffff0000u); }
__device__ __forceinline__ float silu_f(float v) { return v / (1.0f + __expf(-v)); }

// ---------------- weight transpose+bf16 prep into workspace ----------------
// ws layout (each matrix 128x128 = 16384 bf16, stored as WT[n][k] = W[k][n]):
//   l*6 + {0:WaT, 1:WbT, 2:We2T, 3:Wh1aT, 4:Wh1bT, 5:Wh2T}, 12:W_outT, 13:Wn1T
__global__ void prep_weights(const float* __restrict__ We1, const float* __restrict__ We2,
                             const float* __restrict__ Wh1, const float* __restrict__ Wh2,
                             const float* __restrict__ W_out, const float* __restrict__ Wn1,
                             unsigned short* __restrict__ ws) {
    int gid = blockIdx.x * blockDim.x + threadIdx.x;
    if (gid >= 14 * 16384) return;
    int mtx = gid >> 14;
    int el  = gid & 16383;
    int n = el >> 7, k = el & 127;
    int l    = (mtx < 12) ? (mtx / 6) : 0;
    int kind = (mtx < 12) ? (mtx % 6) : (6 + (mtx - 12));
    float v = 0.f;
    switch (kind) {
        case 0: v = We1[(l*257 +       k)*128 + n]; break;   // Wa = We1[l, :128]
        case 1: v = We1[(l*257 + 128 + k)*128 + n]; break;   // Wb = We1[l, 128:256]
        case 2: v = We2[(l*128 +       k)*128 + n]; break;
        case 3: v = Wh1[(l*256 +       k)*128 + n]; break;   // Wh1a
        case 4: v = Wh1[(l*256 + 128 + k)*128 + n]; break;   // Wh1b
        case 5: v = Wh2[(l*128 +       k)*128 + n]; break;
        case 6: v = W_out[k*128 + n]; break;
        case 7: v = Wn1[k*128 + n]; break;
    }
    ws[gid] = f2bf(v);
}

#define MFMA16(ACC, A, B) (ACC) = __builtin_amdgcn_mfma_f32_16x16x32_bf16((A), (B), (ACC), 0, 0, 0)

// ---------------- main fused kernel ----------------
__global__ __launch_bounds__(512, 2) void sake_kernel(
    const float* __restrict__ h,   const float* __restrict__ x,
    const float* __restrict__ W_in,const float* __restrict__ b_in,
    const float* __restrict__ We1, const float* __restrict__ be1,
    const float* __restrict__ be2, const float* __restrict__ bh1,
    const float* __restrict__ bh2, const float* __restrict__ b_out,
    const float* __restrict__ bn1, const float* __restrict__ Wn2,
    const float* __restrict__ bn2, const unsigned short* __restrict__ wt,
    float* __restrict__ out)
{
    __shared__ __align__(16) float          s_d2[32*32];      // 4 KB
    __shared__ __align__(16) float          s_hg[32*129];     // 16.1 KB fp32 residual
    __shared__ __align__(16) unsigned short s_mimj[32*264];   // 16.9 KB (mi|mj+be1); reused: u-stage / g fp32
    __shared__ __align__(16) unsigned short s_A1[32*136];     // 8.5 KB bf16 A-stage (hgb)
    __shared__ __align__(16) unsigned short s_A2[32*136];     // 8.5 KB bf16 A-stage (agg / ho)
    __shared__ __align__(16) unsigned short s_we2[128*136];   // 34 KB We2^T, padded stride
    __shared__ __align__(16) float          s_wd[128];
    __shared__ __align__(16) float          s_x[32*4];
    __shared__ __align__(16) float          s_ep[256];

    const int tid  = threadIdx.x;
    const int b    = blockIdx.x;
    const int w    = tid >> 6;        // wave 0..7
    const int lane = tid & 63;
    const int quad = lane >> 4;
    const int lm   = lane & 15;
    const int mt   = w & 1;           // row-half for 32-row GEMMs
    const int ng   = w >> 1;          // col-tile group

    // ---- load x, d2, hg = h@W_in + b_in ----
    if (tid < 32) {
        s_x[tid*4+0] = x[(b*32+tid)*3+0];
        s_x[tid*4+1] = x[(b*32+tid)*3+1];
        s_x[tid*4+2] = x[(b*32+tid)*3+2];
    }
    __syncthreads();
    for (int p = tid; p < 1024; p += 512) {
        int i = p >> 5, j = p & 31;
        float dx = s_x[i*4+0]-s_x[j*4+0];
        float dy = s_x[i*4+1]-s_x[j*4+1];
        float dz = s_x[i*4+2]-s_x[j*4+2];
        s_d2[p] = dx*dx + dy*dy + dz*dz;
    }
    {
        int k = tid & 127, mg = tid >> 7;   // mg 0..3 -> 8 rows each
        float c0 = W_in[       k], c1 = W_in[ 128+k], c2 = W_in[ 256+k], c3 = W_in[ 384+k];
        float c4 = W_in[ 512+k], c5 = W_in[ 640+k], c6 = W_in[ 768+k], c7 = W_in[ 896+k];
        float c8 = W_in[1024+k], c9 = W_in[1152+k], c10= W_in[1280+k], c11= W_in[1408+k];
        float c12= W_in[1536+k], c13= W_in[1664+k], c14= W_in[1792+k], c15= W_in[1920+k];
        float bi = b_in[k];
        for (int rr = 0; rr < 8; rr++) {
            int m = mg*8 + rr;
            const float4* h4 = (const float4*)(h + (size_t)(b*32 + m)*16);
            float4 h0 = h4[0], h1 = h4[1], h2 = h4[2], h3 = h4[3];
            float acc = bi
                + h0.x*c0  + h0.y*c1  + h0.z*c2  + h0.w*c3
                + h1.x*c4  + h1.y*c5  + h1.z*c6  + h1.w*c7
                + h2.x*c8  + h2.y*c9  + h2.z*c10 + h2.w*c11
                + h3.x*c12 + h3.y*c13 + h3.z*c14 + h3.w*c15;
            s_hg[m*129 + k] = acc;
        }
    }
    __syncthreads();

    for (int l = 0; l < 2; l++) {
        // ---- stage hg -> bf16 A1, load wd, stage We2^T -> LDS ----
        {
            int m = tid >> 4, c = (tid & 15) * 8;
            #pragma unroll
            for (int q = 0; q < 8; q++) s_A1[m*136 + c + q] = f2bf(s_hg[m*129 + c + q]);
        }
        if (tid < 128) s_wd[tid] = We1[(l*257 + 256)*128 + tid];
        {   // 128 rows x 128 shorts; each thread copies 64 B
            const unsigned short* we2t = wt + (((size_t)l*6 + 2) << 14);
            int r = tid >> 2, part = tid & 3;
            const uint4* src = (const uint4*)(we2t + r*128 + part*32);
            uint4* dst = (uint4*)(&s_we2[r*136 + part*32]);
            dst[0] = src[0]; dst[1] = src[1]; dst[2] = src[2]; dst[3] = src[3];
        }
        __syncthreads();

        // ---- mi | mj GEMM: [32x128] @ [Wa | Wb] -> s_mimj (be1 folded into mj) ----
        #pragma unroll 1
        for (int t4 = 0; t4 < 4; t4++) {
            int nt = ng + t4*4;                       // 0..15
            const unsigned short* bt = wt + (((size_t)l*6 + (nt < 8 ? 0 : 1)) << 14);
            int ncl = (nt & 7)*16 + lm;
            f32x4 acc = {0.f,0.f,0.f,0.f};
            #pragma unroll
            for (int kb = 0; kb < 4; kb++) {
                bf16x8 a  = *(const bf16x8*)&s_A1[(mt*16+lm)*136 + kb*32 + quad*8];
                bf16x8 bb = *(const bf16x8*)&bt[ncl*128 + kb*32 + quad*8];
                MFMA16(acc, a, bb);
            }
            int c = nt*16 + lm;
            float bias = (nt >= 8) ? be1[l*128 + ncl] : 0.0f;
            s_mimj[(mt*16 + quad*4 + 0)*264 + c] = f2bf(acc.x + bias);
            s_mimj[(mt*16 + quad*4 + 1)*264 + c] = f2bf(acc.y + bias);
            s_mimj[(mt*16 + quad*4 + 2)*264 + c] = f2bf(acc.z + bias);
            s_mimj[(mt*16 + quad*4 + 3)*264 + c] = f2bf(acc.w + bias);
        }
        __syncthreads();

        // ---- pair phase: silu1 -> (1024x128)@We2 -> silu2 -> mask -> agg ----
        {
            const float be2_0 = be2[l*128 +   0 + lm], be2_1 = be2[l*128 +  16 + lm];
            const float be2_2 = be2[l*128 +  32 + lm], be2_3 = be2[l*128 +  48 + lm];
            const float be2_4 = be2[l*128 +  64 + lm], be2_5 = be2[l*128 +  80 + lm];
            const float be2_6 = be2[l*128 +  96 + lm], be2_7 = be2[l*128 + 112 + lm];

            #pragma unroll 1
            for (int ii = 0; ii < 4; ii++) {
                const int i = ii*8 + w;               // wave owns row i fully
                float vs0=0.f,vs1=0.f,vs2=0.f,vs3=0.f,vs4=0.f,vs5=0.f,vs6=0.f,vs7=0.f;
                // mi is i-dependent only: load packed once per row
                const uint4 miu0 = *(const uint4*)&s_mimj[i*264 +  0 + quad*8];
                const uint4 miu1 = *(const uint4*)&s_mimj[i*264 + 32 + quad*8];
                const uint4 miu2 = *(const uint4*)&s_mimj[i*264 + 64 + quad*8];
                const uint4 miu3 = *(const uint4*)&s_mimj[i*264 + 96 + quad*8];
                #pragma unroll 1
                for (int g = 0; g < 2; g++) {
                    const int j = g*16 + lm;
                    const float d2v = s_d2[i*32 + j];
                    bf16x8 af0, af1, af2, af3;
#define MAKE_AF(KB, MIU, AF) { \
    const uint4 mju = *(const uint4*)&s_mimj[j*264 + 128 + (KB)*32 + quad*8]; \
    const float4 wa = *(const float4*)&s_wd[(KB)*32 + quad*8]; \
    const float4 wb = *(const float4*)&s_wd[(KB)*32 + quad*8 + 4]; \
    uint4 au; \
    au.x = packbf(silu_f(bflo(MIU.x)+bflo(mju.x)+d2v*wa.x), silu_f(bfhi(MIU.x)+bfhi(mju.x)+d2v*wa.y)); \
    au.y = packbf(silu_f(bflo(MIU.y)+bflo(mju.y)+d2v*wa.z), silu_f(bfhi(MIU.y)+bfhi(mju.y)+d2v*wa.w)); \
    au.z = packbf(silu_f(bflo(MIU.z)+bflo(mju.z)+d2v*wb.x), silu_f(bfhi(MIU.z)+bfhi(mju.z)+d2v*wb.y)); \
    au.w = packbf(silu_f(bflo(MIU.w)+bflo(mju.w)+d2v*wb.z), silu_f(bfhi(MIU.w)+bfhi(mju.w)+d2v*wb.w)); \
    AF = __builtin_bit_cast(bf16x8, au); }
                    MAKE_AF(0, miu0, af0) MAKE_AF(1, miu1, af1)
                    MAKE_AF(2, miu2, af2) MAKE_AF(3, miu3, af3)
#undef MAKE_AF
                    const int jb = g*16 + quad*4;
                    const float mk0 = (s_d2[i*32 + jb + 0] < 1.0f && (jb+0) != i) ? 1.f : 0.f;
                    const float mk1 = (s_d2[i*32 + jb + 1] < 1.0f && (jb+1) != i) ? 1.f : 0.f;
                    const float mk2 = (s_d2[i*32 + jb + 2] < 1.0f && (jb+2) != i) ? 1.f : 0.f;
                    const float mk3 = (s_d2[i*32 + jb + 3] < 1.0f && (jb+3) != i) ? 1.f : 0.f;
#define NT_BODY(NT, VS) { \
    const unsigned short* bp = &s_we2[((NT)*16+lm)*136 + quad*8]; \
    f32x4 acc = {0.f,0.f,0.f,0.f}; \
    MFMA16(acc, af0, *(const bf16x8*)(bp      )); \
    MFMA16(acc, af1, *(const bf16x8*)(bp +  32)); \
    MFMA16(acc, af2, *(const bf16x8*)(bp +  64)); \
    MFMA16(acc, af3, *(const bf16x8*)(bp +  96)); \
    VS += mk0*silu_f(acc.x + be2_##NT) + mk1*silu_f(acc.y + be2_##NT) \
        + mk2*silu_f(acc.z + be2_##NT) + mk3*silu_f(acc.w + be2_##NT); }
                    NT_BODY(0, vs0) NT_BODY(1, vs1) NT_BODY(2, vs2) NT_BODY(3, vs3)
                    NT_BODY(4, vs4) NT_BODY(5, vs5) NT_BODY(6, vs6) NT_BODY(7, vs7)
#undef NT_BODY
                }
#define RED(NT, VS) { float v = VS; v += __shfl_xor(v, 16); v += __shfl_xor(v, 32); \
    if (lane < 16) s_A2[i*136 + (NT)*16 + lane] = f2bf(v); }
                RED(0, vs0) RED(1, vs1) RED(2, vs2) RED(3, vs3)
                RED(4, vs4) RED(5, vs5) RED(6, vs6) RED(7, vs7)
#undef RED
            }
        }
        __syncthreads();

        // ---- u = silu(hg@Wh1a + agg@Wh1b + bh1) -> s_u (reuses s_mimj, stride 136) ----
        unsigned short* s_u = s_mimj;
        {
            const unsigned short* w1a = wt + (((size_t)l*6 + 3) << 14);
            const unsigned short* w1b = wt + (((size_t)l*6 + 4) << 14);
#define U_GEMM(T2) { \
    const int nt = ng + (T2)*4, ncl = nt*16 + lm; \
    f32x4 acc = {0.f,0.f,0.f,0.f}; \
    _Pragma("unroll") \
    for (int kb = 0; kb < 4; kb++) { \
        bf16x8 a  = *(const bf16x8*)&s_A1[(mt*16+lm)*136 + kb*32 + quad*8]; \
        bf16x8 bb = *(const bf16x8*)&w1a[ncl*128 + kb*32 + quad*8]; \
        MFMA16(acc, a, bb); } \
    _Pragma("unroll") \
    for (int kb = 0; kb < 4; kb++) { \
        bf16x8 a  = *(const bf16x8*)&s_A2[(mt*16+lm)*136 + kb*32 + quad*8]; \
        bf16x8 bb = *(const bf16x8*)&w1b[ncl*128 + kb*32 + quad*8]; \
        MFMA16(acc, a, bb); } \
    const float bh = bh1[l*128 + ncl]; \
    s_u[(mt*16 + quad*4 + 0)*136 + ncl] = f2bf(silu_f(acc.x + bh)); \
    s_u[(mt*16 + quad*4 + 1)*136 + ncl] = f2bf(silu_f(acc.y + bh)); \
    s_u[(mt*16 + quad*4 + 2)*136 + ncl] = f2bf(silu_f(acc.z + bh)); \
    s_u[(mt*16 + quad*4 + 3)*136 + ncl] = f2bf(silu_f(acc.w + bh)); }
            U_GEMM(0) U_GEMM(1)
#undef U_GEMM
        }
        __syncthreads();

        // ---- hg += u@Wh2 + bh2 ----
        {
            const unsigned short* w2 = wt + (((size_t)l*6 + 5) << 14);
#define H_GEMM(T2) { \
    const int nt = ng + (T2)*4, ncl = nt*16 + lm; \
    f32x4 acc = {0.f,0.f,0.f,0.f}; \
    _Pragma("unroll") \
    for (int kb = 0; kb < 4; kb++) { \
        bf16x8 a  = *(const bf16x8*)&s_u[(mt*16+lm)*136 + kb*32 + quad*8]; \
        bf16x8 bb = *(const bf16x8*)&w2[ncl*128 + kb*32 + quad*8]; \
        MFMA16(acc, a, bb); } \
    const float bh = bh2[l*128 + ncl]; \
    s_hg[(mt*16 + quad*4 + 0)*129 + ncl] += acc.x + bh; \
    s_hg[(mt*16 + quad*4 + 1)*129 + ncl] += acc.y + bh; \
    s_hg[(mt*16 + quad*4 + 2)*129 + ncl] += acc.z + bh; \
    s_hg[(mt*16 + quad*4 + 3)*129 + ncl] += acc.w + bh; }
            H_GEMM(0) H_GEMM(1)
#undef H_GEMM
        }
        __syncthreads();
    }

    // ---- output head ----
    {
        int m = tid >> 4, c = (tid & 15) * 8;
        #pragma unroll
        for (int q = 0; q < 8; q++) s_A1[m*136 + c + q] = f2bf(s_hg[m*129 + c + q]);
    }
    __syncthreads();
    {   // ho = hg@W_out + b_out -> A2 (bf16)
        const unsigned short* wo = wt + ((size_t)12 << 14);
#define O_GEMM(T2) { \
    const int nt = ng + (T2)*4, ncl = nt*16 + lm; \
    f32x4 acc = {0.f,0.f,0.f,0.f}; \
    _Pragma("unroll") \
    for (int kb = 0; kb < 4; kb++) { \
        bf16x8 a  = *(const bf16x8*)&s_A1[(mt*16+lm)*136 + kb*32 + quad*8]; \
        bf16x8 bb = *(const bf16x8*)&wo[ncl*128 + kb*32 + quad*8]; \
        MFMA16(acc, a, bb); } \
    const float bo = b_out[ncl]; \
    s_A2[(mt*16 + quad*4 + 0)*136 + ncl] = f2bf(acc.x + bo); \
    s_A2[(mt*16 + quad*4 + 1)*136 + ncl] = f2bf(acc.y + bo); \
    s_A2[(mt*16 + quad*4 + 2)*136 + ncl] = f2bf(acc.z + bo); \
    s_A2[(mt*16 + quad*4 + 3)*136 + ncl] = f2bf(acc.w + bo); }
        O_GEMM(0) O_GEMM(1)
#undef O_GEMM
    }
    __syncthreads();
    float* s_g = (float*)s_mimj;                           // reuse (g is 32x129 fp32)
    {   // g = silu(ho@Wn1 + bn1) -> s_g fp32
        const unsigned short* wn1 = wt + ((size_t)13 << 14);
#define G_GEMM(T2) { \
    const int nt = ng + (T2)*4, ncl = nt*16 + lm; \
    f32x4 acc = {0.f,0.f,0.f,0.f}; \
    _Pragma("unroll") \
    for (int kb = 0; kb < 4; kb++) { \
        bf16x8 a  = *(const bf16x8*)&s_A2[(mt*16+lm)*136 + kb*32 + quad*8]; \
        bf16x8 bb = *(const bf16x8*)&wn1[ncl*128 + kb*32 + quad*8]; \
        MFMA16(acc, a, bb); } \
    const float bn = bn1[ncl]; \
    s_g[(mt*16 + quad*4 + 0)*129 + ncl] = silu_f(acc.x + bn); \
    s_g[(mt*16 + quad*4 + 1)*129 + ncl] = silu_f(acc.y + bn); \
    s_g[(mt*16 + quad*4 + 2)*129 + ncl] = silu_f(acc.z + bn); \
    s_g[(mt*16 + quad*4 + 3)*129 + ncl] = silu_f(acc.w + bn); }
        G_GEMM(0) G_GEMM(1)
#undef G_GEMM
    }
    __syncthreads();
    // e = g @ Wn2 + bn2 ; out[b] = sum_m e[m]
    if (tid < 256) {
        int m = tid >> 3, s = tid & 7;
        float acc = 0.f;
        #pragma unroll
        for (int q = 0; q < 16; q++) {
            int hh = s*16 + q;
            acc += s_g[m*129 + hh] * Wn2[hh];
        }
        s_ep[tid] = acc;
    }
    __syncthreads();
    if (tid < 32) {
        float e = bn2[0];
        #pragma unroll
        for (int s = 0; s < 8; s++) e += s_ep[tid*8 + s];
        #pragma unroll
        for (int off = 16; off >= 1; off >>= 1) e += __shfl_down(e, off, 32);
        if (tid == 0) out[b] = e;
    }
}

extern "C" void kernel_launch(void* const* d_in, const int* in_sizes, int n_in,
                              void* d_out, int out_size, void* d_ws, size_t ws_size,
                              hipStream_t stream) {
    const float* h     = (const float*)d_in[0];
    const float* x     = (const float*)d_in[1];
    const float* W_in  = (const float*)d_in[3];
    const float* b_in  = (const float*)d_in[4];
    const float* We1   = (const float*)d_in[5];
    const float* be1   = (const float*)d_in[6];
    const float* We2   = (const float*)d_in[7];
    const float* be2   = (const float*)d_in[8];
    const float* Wh1   = (const float*)d_in[9];
    const float* bh1   = (const float*)d_in[10];
    const float* Wh2   = (const float*)d_in[11];
    const float* bh2   = (const float*)d_in[12];
    const float* W_out = (const float*)d_in[13];
    const float* b_out = (const float*)d_in[14];
    const float* Wn1   = (const float*)d_in[15];
    const float* bn1   = (const float*)d_in[16];
    const float* Wn2   = (const float*)d_in[17];
    const float* bn2   = (const float*)d_in[18];
    unsigned short* ws = (unsigned short*)d_ws;   // needs 14*16384*2 = 448 KB
    float* outp = (float*)d_out;

    prep_weights<<<896, 256, 0, stream>>>(We1, We2, Wh1, Wh2, W_out, Wn1, ws);
    sake_kernel<<<NB, 512, 0, stream>>>(h, x, W_in, b_in, We1, be1, be2, bh1, bh2,
                                        b_out, bn1, Wn2, bn2, ws, outp);
}

// Round 6
// 316.699 us; speedup vs baseline: 2.1766x; 1.0870x over previous
//
#include <hip/hip_runtime.h>
#include <hip/hip_bf16.h>

// SAKE GNN: B=512 graphs, M=32 atoms, H=128, L=2 layers, F_IN=16.
// Block = one graph, 512 threads (8 waves). All GEMMs via mfma_f32_16x16x32_bf16.
//
// R6: kill the last scratch spills (R5: 75 MB WRITE = vs0..7/miu spilled
// across the unroll-1 g-loop) by restructuring the pair phase:
//  - both g-halves' A-fragments built up front (32 regs),
//  - inner nt-loop (#pragma unroll 1, be2 from LDS) reads each We2^T B-frag
//    ONCE and feeds both halves (8 MFMAs per 4 ds_read_b128 -> half the LDS
//    B traffic),
//  - per-nt partial is shfl-reduced and accumulated straight into fp32 LDS
//    s_aggf (no register state lives across ANY loop iteration).

#define NB 512

typedef __bf16 bf16x8 __attribute__((ext_vector_type(8)));
typedef float f32x4 __attribute__((ext_vector_type(4)));

__device__ __forceinline__ unsigned short f2bf(float f) {
    unsigned int u = __float_as_uint(f);
    u = u + 0x7FFFu + ((u >> 16) & 1u);   // RNE
    return (unsigned short)(u >> 16);
}
__device__ __forceinline__ unsigned int packbf(float lo, float hi) {
    return (unsigned int)f2bf(lo) | ((unsigned int)f2bf(hi) << 16);
}
__device__ __forceinline__ float bflo(unsigned int u) { return __uint_as_float(u << 16); }
__device__ __forceinline__ float bfhi(unsigned int u) { return __uint_as_float(u & 0xffff0000u); }
__device__ __forceinline__ float silu_f(float v) { return v / (1.0f + __expf(-v)); }

// ---------------- weight transpose+bf16 prep into workspace ----------------
// ws layout (each matrix 128x128 = 16384 bf16, stored as WT[n][k] = W[k][n]):
//   l*6 + {0:WaT, 1:WbT, 2:We2T, 3:Wh1aT, 4:Wh1bT, 5:Wh2T}, 12:W_outT, 13:Wn1T
__global__ void prep_weights(const float* __restrict__ We1, const float* __restrict__ We2,
                             const float* __restrict__ Wh1, const float* __restrict__ Wh2,
                             const float* __restrict__ W_out, const float* __restrict__ Wn1,
                             unsigned short* __restrict__ ws) {
    int gid = blockIdx.x * blockDim.x + threadIdx.x;
    if (gid >= 14 * 16384) return;
    int mtx = gid >> 14;
    int el  = gid & 16383;
    int n = el >> 7, k = el & 127;
    int l    = (mtx < 12) ? (mtx / 6) : 0;
    int kind = (mtx < 12) ? (mtx % 6) : (6 + (mtx - 12));
    float v = 0.f;
    switch (kind) {
        case 0: v = We1[(l*257 +       k)*128 + n]; break;   // Wa = We1[l, :128]
        case 1: v = We1[(l*257 + 128 + k)*128 + n]; break;   // Wb = We1[l, 128:256]
        case 2: v = We2[(l*128 +       k)*128 + n]; break;
        case 3: v = Wh1[(l*256 +       k)*128 + n]; break;   // Wh1a
        case 4: v = Wh1[(l*256 + 128 + k)*128 + n]; break;   // Wh1b
        case 5: v = Wh2[(l*128 +       k)*128 + n]; break;
        case 6: v = W_out[k*128 + n]; break;
        case 7: v = Wn1[k*128 + n]; break;
    }
    ws[gid] = f2bf(v);
}

#define MFMA16(ACC, A, B) (ACC) = __builtin_amdgcn_mfma_f32_16x16x32_bf16((A), (B), (ACC), 0, 0, 0)

// ---------------- main fused kernel ----------------
__global__ __launch_bounds__(512, 2) void sake_kernel(
    const float* __restrict__ h,   const float* __restrict__ x,
    const float* __restrict__ W_in,const float* __restrict__ b_in,
    const float* __restrict__ We1, const float* __restrict__ be1,
    const float* __restrict__ be2, const float* __restrict__ bh1,
    const float* __restrict__ bh2, const float* __restrict__ b_out,
    const float* __restrict__ bn1, const float* __restrict__ Wn2,
    const float* __restrict__ bn2, const unsigned short* __restrict__ wt,
    float* __restrict__ out)
{
    __shared__ __align__(16) float          s_d2[32*32];      // 4 KB
    __shared__ __align__(16) float          s_hg[32*129];     // 16.1 KB fp32 residual
    __shared__ __align__(16) unsigned short s_mimj[32*264];   // 16.9 KB (mi|mj+be1); reused: u-stage / g fp32
    __shared__ __align__(16) unsigned short s_A1[32*136];     // 8.5 KB bf16 A-stage (hgb)
    __shared__ __align__(16) unsigned short s_A2[32*136];     // 8.5 KB bf16 A-stage (agg / ho)
    __shared__ __align__(16) unsigned short s_we2[128*136];   // 34 KB We2^T, padded stride
    __shared__ __align__(16) float          s_aggf[32*132];   // 16.9 KB fp32 agg accumulator
    __shared__ __align__(16) float          s_wd[128];
    __shared__ __align__(16) float          s_be2[128];
    __shared__ __align__(16) float          s_x[32*4];
    __shared__ __align__(16) float          s_ep[256];

    const int tid  = threadIdx.x;
    const int b    = blockIdx.x;
    const int w    = tid >> 6;        // wave 0..7
    const int lane = tid & 63;
    const int quad = lane >> 4;
    const int lm   = lane & 15;
    const int mt   = w & 1;           // row-half for 32-row GEMMs
    const int ng   = w >> 1;          // col-tile group

    // ---- load x, d2, hg = h@W_in + b_in ----
    if (tid < 32) {
        s_x[tid*4+0] = x[(b*32+tid)*3+0];
        s_x[tid*4+1] = x[(b*32+tid)*3+1];
        s_x[tid*4+2] = x[(b*32+tid)*3+2];
    }
    __syncthreads();
    for (int p = tid; p < 1024; p += 512) {
        int i = p >> 5, j = p & 31;
        float dx = s_x[i*4+0]-s_x[j*4+0];
        float dy = s_x[i*4+1]-s_x[j*4+1];
        float dz = s_x[i*4+2]-s_x[j*4+2];
        s_d2[p] = dx*dx + dy*dy + dz*dz;
    }
    {
        int k = tid & 127, mg = tid >> 7;   // mg 0..3 -> 8 rows each
        float c0 = W_in[       k], c1 = W_in[ 128+k], c2 = W_in[ 256+k], c3 = W_in[ 384+k];
        float c4 = W_in[ 512+k], c5 = W_in[ 640+k], c6 = W_in[ 768+k], c7 = W_in[ 896+k];
        float c8 = W_in[1024+k], c9 = W_in[1152+k], c10= W_in[1280+k], c11= W_in[1408+k];
        float c12= W_in[1536+k], c13= W_in[1664+k], c14= W_in[1792+k], c15= W_in[1920+k];
        float bi = b_in[k];
        for (int rr = 0; rr < 8; rr++) {
            int m = mg*8 + rr;
            const float4* h4 = (const float4*)(h + (size_t)(b*32 + m)*16);
            float4 h0 = h4[0], h1 = h4[1], h2 = h4[2], h3 = h4[3];
            float acc = bi
                + h0.x*c0  + h0.y*c1  + h0.z*c2  + h0.w*c3
                + h1.x*c4  + h1.y*c5  + h1.z*c6  + h1.w*c7
                + h2.x*c8  + h2.y*c9  + h2.z*c10 + h2.w*c11
                + h3.x*c12 + h3.y*c13 + h3.z*c14 + h3.w*c15;
            s_hg[m*129 + k] = acc;
        }
    }
    __syncthreads();

    for (int l = 0; l < 2; l++) {
        // ---- stage hg -> bf16 A1, zero agg, load wd/be2, stage We2^T -> LDS ----
        {
            int m = tid >> 4, c = (tid & 15) * 8;
            #pragma unroll
            for (int q = 0; q < 8; q++) {
                s_A1[m*136 + c + q] = f2bf(s_hg[m*129 + c + q]);
                s_aggf[m*132 + c + q] = 0.0f;
            }
        }
        if (tid < 128) {
            s_wd[tid]  = We1[(l*257 + 256)*128 + tid];
            s_be2[tid] = be2[l*128 + tid];
        }
        {   // 128 rows x 128 shorts; each thread copies 64 B
            const unsigned short* we2t = wt + (((size_t)l*6 + 2) << 14);
            int r = tid >> 2, part = tid & 3;
            const uint4* src = (const uint4*)(we2t + r*128 + part*32);
            uint4* dst = (uint4*)(&s_we2[r*136 + part*32]);
            dst[0] = src[0]; dst[1] = src[1]; dst[2] = src[2]; dst[3] = src[3];
        }
        __syncthreads();

        // ---- mi | mj GEMM: [32x128] @ [Wa | Wb] -> s_mimj (be1 folded into mj) ----
        #pragma unroll 1
        for (int t4 = 0; t4 < 4; t4++) {
            int nt = ng + t4*4;                       // 0..15
            const unsigned short* bt = wt + (((size_t)l*6 + (nt < 8 ? 0 : 1)) << 14);
            int ncl = (nt & 7)*16 + lm;
            f32x4 acc = {0.f,0.f,0.f,0.f};
            #pragma unroll
            for (int kb = 0; kb < 4; kb++) {
                bf16x8 a  = *(const bf16x8*)&s_A1[(mt*16+lm)*136 + kb*32 + quad*8];
                bf16x8 bb = *(const bf16x8*)&bt[ncl*128 + kb*32 + quad*8];
                MFMA16(acc, a, bb);
            }
            int c = nt*16 + lm;
            float bias = (nt >= 8) ? be1[l*128 + ncl] : 0.0f;
            s_mimj[(mt*16 + quad*4 + 0)*264 + c] = f2bf(acc.x + bias);
            s_mimj[(mt*16 + quad*4 + 1)*264 + c] = f2bf(acc.y + bias);
            s_mimj[(mt*16 + quad*4 + 2)*264 + c] = f2bf(acc.z + bias);
            s_mimj[(mt*16 + quad*4 + 3)*264 + c] = f2bf(acc.w + bias);
        }
        __syncthreads();

        // ---- pair phase: silu1 -> (1024x128)@We2 -> silu2 -> mask -> agg ----
        {
            #pragma unroll 1
            for (int ii = 0; ii < 4; ii++) {
                const int i = ii*8 + w;               // wave owns row i fully
                // mi is i-dependent only: packed load once per row
                const uint4 miu0 = *(const uint4*)&s_mimj[i*264 +  0 + quad*8];
                const uint4 miu1 = *(const uint4*)&s_mimj[i*264 + 32 + quad*8];
                const uint4 miu2 = *(const uint4*)&s_mimj[i*264 + 64 + quad*8];
                const uint4 miu3 = *(const uint4*)&s_mimj[i*264 + 96 + quad*8];
                bf16x8 a00, a01, a02, a03;            // g=0: j = lm
                bf16x8 a10, a11, a12, a13;            // g=1: j = 16+lm
#define MAKE_AF(J, KB, MIU, AF) { \
    const uint4 mju = *(const uint4*)&s_mimj[(J)*264 + 128 + (KB)*32 + quad*8]; \
    const float4 wa = *(const float4*)&s_wd[(KB)*32 + quad*8]; \
    const float4 wb = *(const float4*)&s_wd[(KB)*32 + quad*8 + 4]; \
    uint4 au; \
    au.x = packbf(silu_f(bflo(MIU.x)+bflo(mju.x)+d2v*wa.x), silu_f(bfhi(MIU.x)+bfhi(mju.x)+d2v*wa.y)); \
    au.y = packbf(silu_f(bflo(MIU.y)+bflo(mju.y)+d2v*wa.z), silu_f(bfhi(MIU.y)+bfhi(mju.y)+d2v*wa.w)); \
    au.z = packbf(silu_f(bflo(MIU.z)+bflo(mju.z)+d2v*wb.x), silu_f(bfhi(MIU.z)+bfhi(mju.z)+d2v*wb.y)); \
    au.w = packbf(silu_f(bflo(MIU.w)+bflo(mju.w)+d2v*wb.z), silu_f(bfhi(MIU.w)+bfhi(mju.w)+d2v*wb.w)); \
    AF = __builtin_bit_cast(bf16x8, au); }
                {
                    const int j = lm;
                    const float d2v = s_d2[i*32 + j];
                    MAKE_AF(j, 0, miu0, a00) MAKE_AF(j, 1, miu1, a01)
                    MAKE_AF(j, 2, miu2, a02) MAKE_AF(j, 3, miu3, a03)
                }
                {
                    const int j = 16 + lm;
                    const float d2v = s_d2[i*32 + j];
                    MAKE_AF(j, 0, miu0, a10) MAKE_AF(j, 1, miu1, a11)
                    MAKE_AF(j, 2, miu2, a12) MAKE_AF(j, 3, miu3, a13)
                }
#undef MAKE_AF
                const int jb0 = quad*4, jb1 = 16 + quad*4;
                const float mk00 = (s_d2[i*32 + jb0 + 0] < 1.0f && (jb0+0) != i) ? 1.f : 0.f;
                const float mk01 = (s_d2[i*32 + jb0 + 1] < 1.0f && (jb0+1) != i) ? 1.f : 0.f;
                const float mk02 = (s_d2[i*32 + jb0 + 2] < 1.0f && (jb0+2) != i) ? 1.f : 0.f;
                const float mk03 = (s_d2[i*32 + jb0 + 3] < 1.0f && (jb0+3) != i) ? 1.f : 0.f;
                const float mk10 = (s_d2[i*32 + jb1 + 0] < 1.0f && (jb1+0) != i) ? 1.f : 0.f;
                const float mk11 = (s_d2[i*32 + jb1 + 1] < 1.0f && (jb1+1) != i) ? 1.f : 0.f;
                const float mk12 = (s_d2[i*32 + jb1 + 2] < 1.0f && (jb1+2) != i) ? 1.f : 0.f;
                const float mk13 = (s_d2[i*32 + jb1 + 3] < 1.0f && (jb1+3) != i) ? 1.f : 0.f;

                #pragma unroll 1
                for (int nt = 0; nt < 8; nt++) {
                    const unsigned short* bp = &s_we2[(nt*16+lm)*136 + quad*8];
                    const bf16x8 b0 = *(const bf16x8*)(bp      );
                    const bf16x8 b1 = *(const bf16x8*)(bp +  32);
                    const bf16x8 b2 = *(const bf16x8*)(bp +  64);
                    const bf16x8 b3 = *(const bf16x8*)(bp +  96);
                    f32x4 ac0 = {0.f,0.f,0.f,0.f};
                    f32x4 ac1 = {0.f,0.f,0.f,0.f};
                    MFMA16(ac0, a00, b0); MFMA16(ac0, a01, b1);
                    MFMA16(ac0, a02, b2); MFMA16(ac0, a03, b3);
                    MFMA16(ac1, a10, b0); MFMA16(ac1, a11, b1);
                    MFMA16(ac1, a12, b2); MFMA16(ac1, a13, b3);
                    const float bv = s_be2[nt*16 + lm];
                    float part = mk00*silu_f(ac0.x + bv) + mk01*silu_f(ac0.y + bv)
                               + mk02*silu_f(ac0.z + bv) + mk03*silu_f(ac0.w + bv)
                               + mk10*silu_f(ac1.x + bv) + mk11*silu_f(ac1.y + bv)
                               + mk12*silu_f(ac1.z + bv) + mk13*silu_f(ac1.w + bv);
                    part += __shfl_xor(part, 16);
                    part += __shfl_xor(part, 32);
                    if (lane < 16) s_aggf[i*132 + nt*16 + lane] += part;
                }
            }
        }
        __syncthreads();
        {   // agg fp32 -> bf16 A-stage
            int m = tid >> 4, c = (tid & 15) * 8;
            #pragma unroll
            for (int q = 0; q < 8; q++) s_A2[m*136 + c + q] = f2bf(s_aggf[m*132 + c + q]);
        }
        __syncthreads();

        // ---- u = silu(hg@Wh1a + agg@Wh1b + bh1) -> s_u (reuses s_mimj, stride 136) ----
        unsigned short* s_u = s_mimj;
        {
            const unsigned short* w1a = wt + (((size_t)l*6 + 3) << 14);
            const unsigned short* w1b = wt + (((size_t)l*6 + 4) << 14);
#define U_GEMM(T2) { \
    const int nt = ng + (T2)*4, ncl = nt*16 + lm; \
    f32x4 acc = {0.f,0.f,0.f,0.f}; \
    _Pragma("unroll") \
    for (int kb = 0; kb < 4; kb++) { \
        bf16x8 a  = *(const bf16x8*)&s_A1[(mt*16+lm)*136 + kb*32 + quad*8]; \
        bf16x8 bb = *(const bf16x8*)&w1a[ncl*128 + kb*32 + quad*8]; \
        MFMA16(acc, a, bb); } \
    _Pragma("unroll") \
    for (int kb = 0; kb < 4; kb++) { \
        bf16x8 a  = *(const bf16x8*)&s_A2[(mt*16+lm)*136 + kb*32 + quad*8]; \
        bf16x8 bb = *(const bf16x8*)&w1b[ncl*128 + kb*32 + quad*8]; \
        MFMA16(acc, a, bb); } \
    const float bh = bh1[l*128 + ncl]; \
    s_u[(mt*16 + quad*4 + 0)*136 + ncl] = f2bf(silu_f(acc.x + bh)); \
    s_u[(mt*16 + quad*4 + 1)*136 + ncl] = f2bf(silu_f(acc.y + bh)); \
    s_u[(mt*16 + quad*4 + 2)*136 + ncl] = f2bf(silu_f(acc.z + bh)); \
    s_u[(mt*16 + quad*4 + 3)*136 + ncl] = f2bf(silu_f(acc.w + bh)); }
            U_GEMM(0) U_GEMM(1)
#undef U_GEMM
        }
        __syncthreads();

        // ---- hg += u@Wh2 + bh2 ----
        {
            const unsigned short* w2 = wt + (((size_t)l*6 + 5) << 14);
#define H_GEMM(T2) { \
    const int nt = ng + (T2)*4, ncl = nt*16 + lm; \
    f32x4 acc = {0.f,0.f,0.f,0.f}; \
    _Pragma("unroll") \
    for (int kb = 0; kb < 4; kb++) { \
        bf16x8 a  = *(const bf16x8*)&s_u[(mt*16+lm)*136 + kb*32 + quad*8]; \
        bf16x8 bb = *(const bf16x8*)&w2[ncl*128 + kb*32 + quad*8]; \
        MFMA16(acc, a, bb); } \
    const float bh = bh2[l*128 + ncl]; \
    s_hg[(mt*16 + quad*4 + 0)*129 + ncl] += acc.x + bh; \
    s_hg[(mt*16 + quad*4 + 1)*129 + ncl] += acc.y + bh; \
    s_hg[(mt*16 + quad*4 + 2)*129 + ncl] += acc.z + bh; \
    s_hg[(mt*16 + quad*4 + 3)*129 + ncl] += acc.w + bh; }
            H_GEMM(0) H_GEMM(1)
#undef H_GEMM
        }
        __syncthreads();
    }

    // ---- output head ----
    {
        int m = tid >> 4, c = (tid & 15) * 8;
        #pragma unroll
        for (int q = 0; q < 8; q++) s_A1[m*136 + c + q] = f2bf(s_hg[m*129 + c + q]);
    }
    __syncthreads();
    {   // ho = hg@W_out + b_out -> A2 (bf16)
        const unsigned short* wo = wt + ((size_t)12 << 14);
#define O_GEMM(T2) { \
    const int nt = ng + (T2)*4, ncl = nt*16 + lm; \
    f32x4 acc = {0.f,0.f,0.f,0.f}; \
    _Pragma("unroll") \
    for (int kb = 0; kb < 4; kb++) { \
        bf16x8 a  = *(const bf16x8*)&s_A1[(mt*16+lm)*136 + kb*32 + quad*8]; \
        bf16x8 bb = *(const bf16x8*)&wo[ncl*128 + kb*32 + quad*8]; \
        MFMA16(acc, a, bb); } \
    const float bo = b_out[ncl]; \
    s_A2[(mt*16 + quad*4 + 0)*136 + ncl] = f2bf(acc.x + bo); \
    s_A2[(mt*16 + quad*4 + 1)*136 + ncl] = f2bf(acc.y + bo); \
    s_A2[(mt*16 + quad*4 + 2)*136 + ncl] = f2bf(acc.z + bo); \
    s_A2[(mt*16 + quad*4 + 3)*136 + ncl] = f2bf(acc.w + bo); }
        O_GEMM(0) O_GEMM(1)
#undef O_GEMM
    }
    __syncthreads();
    float* s_g = (float*)s_mimj;                           // reuse (g is 32x129 fp32)
    {   // g = silu(ho@Wn1 + bn1) -> s_g fp32
        const unsigned short* wn1 = wt + ((size_t)13 << 14);
#define G_GEMM(T2) { \
    const int nt = ng + (T2)*4, ncl = nt*16 + lm; \
    f32x4 acc = {0.f,0.f,0.f,0.f}; \
    _Pragma("unroll") \
    for (int kb = 0; kb < 4; kb++) { \
        bf16x8 a  = *(const bf16x8*)&s_A2[(mt*16+lm)*136 + kb*32 + quad*8]; \
        bf16x8 bb = *(const bf16x8*)&wn1[ncl*128 + kb*32 + quad*8]; \
        MFMA16(acc, a, bb); } \
    const float bn = bn1[ncl]; \
    s_g[(mt*16 + quad*4 + 0)*129 + ncl] = silu_f(acc.x + bn); \
    s_g[(mt*16 + quad*4 + 1)*129 + ncl] = silu_f(acc.y + bn); \
    s_g[(mt*16 + quad*4 + 2)*129 + ncl] = silu_f(acc.z + bn); \
    s_g[(mt*16 + quad*4 + 3)*129 + ncl] = silu_f(acc.w + bn); }
        G_GEMM(0) G_GEMM(1)
#undef G_GEMM
    }
    __syncthreads();
    // e = g @ Wn2 + bn2 ; out[b] = sum_m e[m]
    if (tid < 256) {
        int m = tid >> 3, s = tid & 7;
        float acc = 0.f;
        #pragma unroll
        for (int q = 0; q < 16; q++) {
            int hh = s*16 + q;
            acc += s_g[m*129 + hh] * Wn2[hh];
        }
        s_ep[tid] = acc;
    }
    __syncthreads();
    if (tid < 32) {
        float e = bn2[0];
        #pragma unroll
        for (int s = 0; s < 8; s++) e += s_ep[tid*8 + s];
        #pragma unroll
        for (int off = 16; off >= 1; off >>= 1) e += __shfl_down(e, off, 32);
        if (tid == 0) out[b] = e;
    }
}

extern "C" void kernel_launch(void* const* d_in, const int* in_sizes, int n_in,
                              void* d_out, int out_size, void* d_ws, size_t ws_size,
                              hipStream_t stream) {
    const float* h     = (const float*)d_in[0];
    const float* x     = (const float*)d_in[1];
    const float* W_in  = (const float*)d_in[3];
    const float* b_in  = (const float*)d_in[4];
    const float* We1   = (const float*)d_in[5];
    const float* be1   = (const float*)d_in[6];
    const float* We2   = (const float*)d_in[7];
    const float* be2   = (const float*)d_in[8];
    const float* Wh1   = (const float*)d_in[9];
    const float* bh1   = (const float*)d_in[10];
    const float* Wh2   = (const float*)d_in[11];
    const float* bh2   = (const float*)d_in[12];
    const float* W_out = (const float*)d_in[13];
    const float* b_out = (const float*)d_in[14];
    const float* Wn1   = (const float*)d_in[15];
    const float* bn1   = (const float*)d_in[16];
    const float* Wn2   = (const float*)d_in[17];
    const float* bn2   = (const float*)d_in[18];
    unsigned short* ws = (unsigned short*)d_ws;   // needs 14*16384*2 = 448 KB
    float* outp = (float*)d_out;

    prep_weights<<<896, 256, 0, stream>>>(We1, We2, Wh1, Wh2, W_out, Wn1, ws);
    sake_kernel<<<NB, 512, 0, stream>>>(h, x, W_in, b_in, We1, be1, be2, bh1, bh2,
                                        b_out, bn1, Wn2, bn2, ws, outp);
}